// Round 3
// baseline (3018.127 us; speedup 1.0000x reference)
//
#include <hip/hip_runtime.h>
#include <hip/hip_bf16.h>

typedef __attribute__((ext_vector_type(8))) short bf16x8;
typedef __attribute__((ext_vector_type(4))) float f32x4;

#define EPB 4096        // edges per partition block
#define NODE_TILE 128   // nodes per bucket / agg block

static __device__ __forceinline__ unsigned short f2bf(float f) {
    union { float f; unsigned u; } v; v.f = f;
    unsigned r = v.u + 0x7FFF + ((v.u >> 16) & 1);
    return (unsigned short)(r >> 16);
}
static __device__ __forceinline__ float bf2f(unsigned short h) {
    union { unsigned u; float f; } v; v.u = ((unsigned)h) << 16;
    return v.f;
}

// ---- convert f32 -> bf16 (4 elems/thread) ----
__global__ __launch_bounds__(256) void cvt_bf16(const float* __restrict__ x,
                                                unsigned short* __restrict__ out, int n4) {
    int i = blockIdx.x * 256 + threadIdx.x;
    if (i >= n4) return;
    float4 v = ((const float4*)x)[i];
    ushort4 o;
    o.x = f2bf(v.x); o.y = f2bf(v.y); o.z = f2bf(v.z); o.w = f2bf(v.w);
    ((ushort4*)out)[i] = o;
}

// ---- build swizzled B = [W_rel | W_root] in MFMA B-fragment order ----
__global__ __launch_bounds__(256) void build_bsw(const float* __restrict__ Wrel,
                                                 const float* __restrict__ Wroot,
                                                 unsigned short* __restrict__ bsw) {
    int idx = blockIdx.x * 256 + threadIdx.x;  // 32768 total
    int j = idx & 7, L = (idx >> 3) & 63, ct = (idx >> 9) & 15, kt = idx >> 13;
    int k = kt * 32 + ((L >> 4) * 8) + j;
    int c = ct * 16 + (L & 15);
    float v = (c < 128) ? Wrel[k * 128 + c] : Wroot[k * 128 + (c - 128)];
    bsw[idx] = f2bf(v);
}

// ---- build swizzled W_lin [256,40] padded to 48 cols ----
__global__ __launch_bounds__(256) void build_bswL(const float* __restrict__ Wlin,
                                                  unsigned short* __restrict__ bsw, int total) {
    int idx = blockIdx.x * 256 + threadIdx.x;  // 12288 total
    if (idx >= total) return;
    int t = idx;
    int j = t & 7; t >>= 3;
    int L = t & 63; t >>= 6;
    int ct = t % 3;
    int kt = t / 3;
    int k = kt * 32 + ((L >> 4) * 8) + j;
    int c = ct * 16 + (L & 15);
    float v = (c < 40) ? Wlin[k * 40 + c] : 0.f;
    bsw[idx] = f2bf(v);
}

// ================= edge partition into dst-buckets (LDS atomics only) =================

// A1: per-block histogram over buckets
__global__ __launch_bounds__(256) void edge_hist(const int* __restrict__ dst,
                                                 int* __restrict__ hist,  // [NBUCK][NBLK]
                                                 int E, int nblk, int nbuck) {
    __shared__ int h[1024];
    int t = threadIdx.x, blk = blockIdx.x;
    for (int i = t; i < nbuck; i += 256) h[i] = 0;
    __syncthreads();
    int e0 = blk * EPB;
#pragma unroll
    for (int it = 0; it < EPB / 256; it++) {
        int e = e0 + it * 256 + t;
        if (e < E) atomicAdd(&h[dst[e] >> 7], 1);
    }
    __syncthreads();
    for (int b = t; b < nbuck; b += 256) hist[b * nblk + blk] = h[b];
}

// A2: bucket totals
__global__ __launch_bounds__(256) void bucket_total(const int* __restrict__ hist,
                                                    int* __restrict__ total, int nblk) {
    __shared__ int s[256];
    int b = blockIdx.x, t = threadIdx.x;
    int v = 0;
    for (int i = t; i < nblk; i += 256) v += hist[b * nblk + i];
    s[t] = v; __syncthreads();
#pragma unroll
    for (int o = 128; o >= 1; o >>= 1) {
        if (t < o) s[t] += s[t + o];
        __syncthreads();
    }
    if (t == 0) total[b] = s[0];
}

// A3: exclusive scan of bucket totals (single block)
__global__ __launch_bounds__(1024) void bucket_scan(const int* __restrict__ total,
                                                    int* __restrict__ base, int nbuck) {
    __shared__ int s[1024];
    int t = threadIdx.x;
    int v = (t < nbuck) ? total[t] : 0;
    s[t] = v; __syncthreads();
#pragma unroll
    for (int o = 1; o < 1024; o <<= 1) {
        int x = (t >= o) ? s[t - o] : 0;
        __syncthreads();
        s[t] += x; __syncthreads();
    }
    if (t < nbuck) base[t] = s[t] - v;
    if (t == 1023) base[nbuck] = s[1023];
}

// A4: per-bucket scan over blocks: hist[b][blk] -> global slot base (in place)
__global__ __launch_bounds__(256) void block_scan(int* __restrict__ hist,
                                                  const int* __restrict__ base, int nblk) {
    __shared__ int s[256];
    __shared__ int carry;
    int b = blockIdx.x, t = threadIdx.x;
    if (t == 0) carry = base[b];
    __syncthreads();
    for (int start = 0; start < nblk; start += 256) {
        int i = start + t;
        int v = (i < nblk) ? hist[b * nblk + i] : 0;
        s[t] = v; __syncthreads();
#pragma unroll
        for (int o = 1; o < 256; o <<= 1) {
            int x = (t >= o) ? s[t - o] : 0;
            __syncthreads();
            s[t] += x; __syncthreads();
        }
        int excl = s[t] - v + carry;
        if (i < nblk) hist[b * nblk + i] = excl;
        if (t == 255) carry += s[255];
        __syncthreads();
    }
}

// A5: scatter packed edge records (ldst<<17 | src) into bucket regions
__global__ __launch_bounds__(256) void edge_part(const int* __restrict__ src,
                                                 const int* __restrict__ dst,
                                                 const int* __restrict__ hist,  // block bases
                                                 int* __restrict__ part,
                                                 int E, int nblk, int nbuck) {
    __shared__ int cur[1024];
    int t = threadIdx.x, blk = blockIdx.x;
    for (int b = t; b < nbuck; b += 256) cur[b] = hist[b * nblk + blk];
    __syncthreads();
    int e0 = blk * EPB;
#pragma unroll
    for (int it = 0; it < EPB / 256; it++) {
        int e = e0 + it * 256 + t;
        if (e < E) {
            int d = dst[e];
            int bucket = d >> 7;
            int pos = atomicAdd(&cur[bucket], 1);
            part[pos] = ((d & 127) << 17) | src[e];
        }
    }
}

// ================= layer GEMM =================
// [N,128]bf16 @ [128,256]bf16 -> xr[N,128]bf16 (cols 0..127), acc[N,128]f32 = cols 128..255 + bias
__global__ __launch_bounds__(256) void gemm_layer(const unsigned short* __restrict__ Abf,
                                                  const unsigned short* __restrict__ Bsw,
                                                  const float* __restrict__ bias,
                                                  unsigned short* __restrict__ xr,
                                                  float* __restrict__ accbuf, int N) {
    int wid = blockIdx.x * 4 + (threadIdx.x >> 6);
    int L = threadIdx.x & 63;
    int r0 = wid * 16;
    if (r0 >= N) return;
    int arow = r0 + (L & 15);
    const bf16x8* Aptr = (const bf16x8*)(Abf + (size_t)arow * 128 + ((L >> 4) * 8));
    const bf16x8* Bptr = ((const bf16x8*)Bsw) + L;
    f32x4 acc[16];
#pragma unroll
    for (int i = 0; i < 16; i++) acc[i] = (f32x4){0.f, 0.f, 0.f, 0.f};
#pragma unroll
    for (int kt = 0; kt < 4; kt++) {
        bf16x8 a = Aptr[kt * 4];
#pragma unroll
        for (int ct = 0; ct < 16; ct++) {
            bf16x8 b = Bptr[(kt * 16 + ct) * 64];
            acc[ct] = __builtin_amdgcn_mfma_f32_16x16x32_bf16(a, b, acc[ct], 0, 0, 0);
        }
    }
    int rbase = r0 + (L >> 4) * 4;
    int cl = L & 15;
#pragma unroll
    for (int ct = 0; ct < 16; ct++) {
        int col = ct * 16 + cl;
#pragma unroll
        for (int r = 0; r < 4; r++) {
            int row = rbase + r;
            float v = acc[ct][r];
            if (col < 128)
                xr[(size_t)row * 128 + col] = f2bf(v);
            else
                accbuf[(size_t)row * 128 + (col - 128)] = v + bias[col - 128];
        }
    }
}

// ================= fused aggregate + relu + bf16 convert =================
// one block per bucket of 128 nodes; 64KB LDS f32 accumulator
__global__ __launch_bounds__(256) void agg_fused(const unsigned short* __restrict__ xr,
                                                 const float* __restrict__ acc,
                                                 const int* __restrict__ bucketBase,
                                                 const int* __restrict__ part,
                                                 unsigned short* __restrict__ out, int N) {
    __shared__ float lds_acc[NODE_TILE * 128];  // 64 KB
    int b = blockIdx.x;
    int t = threadIdx.x;
    int nodes0 = b * NODE_TILE;
    int nn = N - nodes0; if (nn > NODE_TILE) nn = NODE_TILE;

    // init accumulator from acc (root contribution + bias)
    const float4* av = (const float4*)(acc + (size_t)nodes0 * 128);
    float4* lv = (float4*)lds_acc;
    for (int i = t; i < nn * 32; i += 256) lv[i] = av[i];
    __syncthreads();

    // edge loop: wave-broadcast src, coalesced 256B gather, LDS f32 atomic accumulate
    int lo = bucketBase[b], hi = bucketBase[b + 1];
    int w = t >> 6, L = t & 63;
    for (int base = lo + w * 64; base < hi; base += 256) {
        int cnt = hi - base; if (cnt > 64) cnt = 64;
        int rec = (L < cnt) ? part[base + L] : 0;
#pragma unroll 8
        for (int j = 0; j < cnt; j++) {
            int r = __shfl(rec, j, 64);
            int s = r & 0x1FFFF;
            int ld = r >> 17;
            unsigned p = *(const unsigned*)(xr + (size_t)s * 128 + L * 2);
            atomicAdd(&lds_acc[ld * 128 + L * 2],     bf2f((unsigned short)(p & 0xFFFF)));
            atomicAdd(&lds_acc[ld * 128 + L * 2 + 1], bf2f((unsigned short)(p >> 16)));
        }
    }
    __syncthreads();

    // epilogue: relu + bf16 pack, coalesced write
    unsigned* outp = (unsigned*)(out + (size_t)nodes0 * 128);
    const float2* l2 = (const float2*)lds_acc;
    for (int i = t; i < nn * 64; i += 256) {
        float2 f = l2[i];
        unsigned op = ((unsigned)f2bf(fmaxf(f.y, 0.f)) << 16) | (unsigned)f2bf(fmaxf(f.x, 0.f));
        outp[i] = op;
    }
}

// ================= final GEMM + log_softmax =================
__global__ __launch_bounds__(256) void gemm_final(const unsigned short* __restrict__ x1bf,
                                                  const unsigned short* __restrict__ x2bf,
                                                  const unsigned short* __restrict__ Bsw,
                                                  const float* __restrict__ blin,
                                                  float* __restrict__ logits, int N) {
    int wid = blockIdx.x * 4 + (threadIdx.x >> 6);
    int L = threadIdx.x & 63;
    int r0 = wid * 16;
    if (r0 >= N) return;
    int arow = r0 + (L & 15);
    f32x4 acc[3];
#pragma unroll
    for (int i = 0; i < 3; i++) acc[i] = (f32x4){0.f, 0.f, 0.f, 0.f};
#pragma unroll
    for (int kt = 0; kt < 8; kt++) {
        const unsigned short* Ab = (kt < 4) ? x1bf : x2bf;
        int kk = (kt & 3) * 32 + ((L >> 4) * 8);
        bf16x8 a = *((const bf16x8*)(Ab + (size_t)arow * 128 + kk));
#pragma unroll
        for (int ct = 0; ct < 3; ct++) {
            bf16x8 b = ((const bf16x8*)Bsw)[(kt * 3 + ct) * 64 + L];
            acc[ct] = __builtin_amdgcn_mfma_f32_16x16x32_bf16(a, b, acc[ct], 0, 0, 0);
        }
    }
    int rbase = r0 + (L >> 4) * 4;
    int cl = L & 15;
#pragma unroll
    for (int ct = 0; ct < 3; ct++) {
        int col = ct * 16 + cl;
        if (col < 40) {
#pragma unroll
            for (int r = 0; r < 4; r++) {
                logits[(size_t)(rbase + r) * 40 + col] = acc[ct][r] + blin[col];
            }
        }
    }
}

__global__ __launch_bounds__(256) void log_softmax_k(const float* __restrict__ logits,
                                                     float* __restrict__ out, int N) {
    int node = blockIdx.x * 4 + (threadIdx.x >> 6);
    if (node >= N) return;
    int L = threadIdx.x & 63;
    float v = (L < 40) ? logits[(size_t)node * 40 + L] : -__builtin_inff();
    float m = v;
#pragma unroll
    for (int off = 32; off >= 1; off >>= 1) m = fmaxf(m, __shfl_xor(m, off, 64));
    float e = (L < 40) ? __expf(v - m) : 0.f;
    float s = e;
#pragma unroll
    for (int off = 32; off >= 1; off >>= 1) s += __shfl_xor(s, off, 64);
    if (L < 40) out[(size_t)node * 40 + L] = v - m - __logf(s);
}

extern "C" void kernel_launch(void* const* d_in, const int* in_sizes, int n_in,
                              void* d_out, int out_size, void* d_ws, size_t ws_size,
                              hipStream_t stream) {
    const float* x      = (const float*)d_in[0];
    const int*   edge   = (const int*)d_in[1];
    const float* Wrel1  = (const float*)d_in[2];
    const float* brel1  = (const float*)d_in[3];
    const float* Wroot1 = (const float*)d_in[4];
    const float* Wrel2  = (const float*)d_in[5];
    const float* brel2  = (const float*)d_in[6];
    const float* Wroot2 = (const float*)d_in[7];
    const float* Wlin   = (const float*)d_in[8];
    const float* blin   = (const float*)d_in[9];

    const int N = in_sizes[0] / 128;
    const int E = in_sizes[1] / 2;
    const int* src = edge;
    const int* dst = edge + E;

    const int nblk  = (E + EPB - 1) / EPB;          // 391
    const int nbuck = (N + NODE_TILE - 1) / NODE_TILE;  // 782

    char* ws = (char*)d_ws;
    size_t off = 0;
    auto alloc = [&](size_t bytes) -> void* {
        void* p = ws + off;
        off += (bytes + 255) & ~(size_t)255;
        return p;
    };
    unsigned short* xbf  = (unsigned short*)alloc((size_t)N * 128 * 2);  // reused as x2bf
    unsigned short* x1bf = (unsigned short*)alloc((size_t)N * 128 * 2);
    unsigned short* xr   = (unsigned short*)alloc((size_t)N * 128 * 2);
    float* acc1          = (float*)alloc((size_t)N * 128 * 4);           // reused as logits
    float* acc2          = (float*)alloc((size_t)N * 128 * 4);
    unsigned short* bsw1 = (unsigned short*)alloc(32768 * 2);
    unsigned short* bsw2 = (unsigned short*)alloc(32768 * 2);
    unsigned short* bswL = (unsigned short*)alloc(12288 * 2);
    int* hist       = (int*)alloc((size_t)nbuck * nblk * 4);
    int* bucketTot  = (int*)alloc((size_t)nbuck * 4);
    int* bucketBase = (int*)alloc((size_t)(nbuck + 1) * 4);
    int* part       = (int*)alloc((size_t)E * 4);
    unsigned short* x2bf = xbf;
    float* logits        = acc1;

    const int n4 = (N * 128) / 4;
    const int cvtBlocks = (n4 + 255) / 256;
    const int rowTiles = (N + 15) / 16;
    const int gemmBlocks = (rowTiles + 3) / 4;
    const int nodeBlocks = (N + 3) / 4;

    // weight swizzles + input convert
    build_bsw<<<128, 256, 0, stream>>>(Wrel1, Wroot1, bsw1);
    build_bsw<<<128, 256, 0, stream>>>(Wrel2, Wroot2, bsw2);
    build_bswL<<<48, 256, 0, stream>>>(Wlin, bswL, 12288);
    cvt_bf16<<<cvtBlocks, 256, 0, stream>>>(x, xbf, n4);

    // edge partition (once; shared by both layers)
    edge_hist<<<nblk, 256, 0, stream>>>(dst, hist, E, nblk, nbuck);
    bucket_total<<<nbuck, 256, 0, stream>>>(hist, bucketTot, nblk);
    bucket_scan<<<1, 1024, 0, stream>>>(bucketTot, bucketBase, nbuck);
    block_scan<<<nbuck, 256, 0, stream>>>(hist, bucketBase, nblk);
    edge_part<<<nblk, 256, 0, stream>>>(src, dst, hist, part, E, nblk, nbuck);

    // layer 1
    gemm_layer<<<gemmBlocks, 256, 0, stream>>>(xbf, bsw1, brel1, xr, acc1, N);
    agg_fused<<<nbuck, 256, 0, stream>>>(xr, acc1, bucketBase, part, x1bf, N);

    // layer 2
    gemm_layer<<<gemmBlocks, 256, 0, stream>>>(x1bf, bsw2, brel2, xr, acc2, N);
    agg_fused<<<nbuck, 256, 0, stream>>>(xr, acc2, bucketBase, part, x2bf, N);

    // classifier + log_softmax
    gemm_final<<<gemmBlocks, 256, 0, stream>>>(x1bf, x2bf, bswL, blin, logits, N);
    log_softmax_k<<<nodeBlocks, 256, 0, stream>>>(logits, (float*)d_out, N);
}

// Round 4
// 497.224 us; speedup vs baseline: 6.0700x; 6.0700x over previous
//
#include <hip/hip_runtime.h>
#include <hip/hip_bf16.h>

typedef __attribute__((ext_vector_type(8))) short bf16x8;
typedef __attribute__((ext_vector_type(4))) float f32x4;

#define EPB 4096          // edges per partition block
#define BUCKET_BITS 10
#define BUCKET_SIZE 1024  // nodes per bucket

static __device__ __forceinline__ unsigned short f2bf(float f) {
    union { float f; unsigned u; } v; v.f = f;
    unsigned r = v.u + 0x7FFF + ((v.u >> 16) & 1);
    return (unsigned short)(r >> 16);
}
static __device__ __forceinline__ float bf2f(unsigned short h) {
    union { unsigned u; float f; } v; v.u = ((unsigned)h) << 16;
    return v.f;
}

// ---- convert f32 -> bf16 (4 elems/thread) ----
__global__ __launch_bounds__(256) void cvt_bf16(const float* __restrict__ x,
                                                unsigned short* __restrict__ out, int n4) {
    int i = blockIdx.x * 256 + threadIdx.x;
    if (i >= n4) return;
    float4 v = ((const float4*)x)[i];
    ushort4 o;
    o.x = f2bf(v.x); o.y = f2bf(v.y); o.z = f2bf(v.z); o.w = f2bf(v.w);
    ((ushort4*)out)[i] = o;
}

// ---- build swizzled B = [W_rel | W_root] in MFMA B-fragment order ----
__global__ __launch_bounds__(256) void build_bsw(const float* __restrict__ Wrel,
                                                 const float* __restrict__ Wroot,
                                                 unsigned short* __restrict__ bsw) {
    int idx = blockIdx.x * 256 + threadIdx.x;  // 32768 total
    int j = idx & 7, L = (idx >> 3) & 63, ct = (idx >> 9) & 15, kt = idx >> 13;
    int k = kt * 32 + ((L >> 4) * 8) + j;
    int c = ct * 16 + (L & 15);
    float v = (c < 128) ? Wrel[k * 128 + c] : Wroot[k * 128 + (c - 128)];
    bsw[idx] = f2bf(v);
}

// ---- build swizzled W_lin [256,40] padded to 48 cols ----
__global__ __launch_bounds__(256) void build_bswL(const float* __restrict__ Wlin,
                                                  unsigned short* __restrict__ bsw, int total) {
    int idx = blockIdx.x * 256 + threadIdx.x;  // 12288 total
    if (idx >= total) return;
    int t = idx;
    int j = t & 7; t >>= 3;
    int L = t & 63; t >>= 6;
    int ct = t % 3;
    int kt = t / 3;
    int k = kt * 32 + ((L >> 4) * 8) + j;
    int c = ct * 16 + (L & 15);
    float v = (c < 40) ? Wlin[k * 40 + c] : 0.f;
    bsw[idx] = f2bf(v);
}

// ================= atomic-free CSR build =================
// Two-level counting sort: 98 buckets of 1024 dst-nodes, then per-bucket finalize.

// B1: per-block histogram over buckets (LDS atomics only)
__global__ __launch_bounds__(256) void edge_hist(const int* __restrict__ dst,
                                                 int* __restrict__ hist,  // [nbuck][nblk]
                                                 int E, int nblk, int nbuck) {
    __shared__ int h[128];
    int t = threadIdx.x, blk = blockIdx.x;
    if (t < nbuck) h[t] = 0;
    __syncthreads();
    int e0 = blk * EPB;
#pragma unroll
    for (int it = 0; it < EPB / 256; it++) {
        int e = e0 + it * 256 + t;
        if (e < E) atomicAdd(&h[dst[e] >> BUCKET_BITS], 1);
    }
    __syncthreads();
    if (t < nbuck) hist[t * nblk + blk] = h[t];
}

// B2: bucket totals
__global__ __launch_bounds__(256) void bucket_total(const int* __restrict__ hist,
                                                    int* __restrict__ total, int nblk) {
    __shared__ int s[256];
    int b = blockIdx.x, t = threadIdx.x;
    int v = 0;
    for (int i = t; i < nblk; i += 256) v += hist[b * nblk + i];
    s[t] = v; __syncthreads();
#pragma unroll
    for (int o = 128; o >= 1; o >>= 1) {
        if (t < o) s[t] += s[t + o];
        __syncthreads();
    }
    if (t == 0) total[b] = s[0];
}

// B3: exclusive scan of bucket totals (single block, nbuck <= 128)
__global__ __launch_bounds__(128) void bucket_scan(const int* __restrict__ total,
                                                   int* __restrict__ base, int nbuck) {
    __shared__ int s[128];
    int t = threadIdx.x;
    int v = (t < nbuck) ? total[t] : 0;
    s[t] = v; __syncthreads();
#pragma unroll
    for (int o = 1; o < 128; o <<= 1) {
        int x = (t >= o) ? s[t - o] : 0;
        __syncthreads();
        s[t] += x; __syncthreads();
    }
    if (t < nbuck) base[t] = s[t] - v;
    if (t == 127) base[nbuck] = s[127];
}

// B4: per-bucket scan over blocks: hist[b][blk] -> global slot base (in place)
__global__ __launch_bounds__(256) void block_scan(int* __restrict__ hist,
                                                  const int* __restrict__ base, int nblk) {
    __shared__ int s[256];
    __shared__ int carry;
    int b = blockIdx.x, t = threadIdx.x;
    if (t == 0) carry = base[b];
    __syncthreads();
    for (int start = 0; start < nblk; start += 256) {
        int i = start + t;
        int v = (i < nblk) ? hist[b * nblk + i] : 0;
        s[t] = v; __syncthreads();
#pragma unroll
        for (int o = 1; o < 256; o <<= 1) {
            int x = (t >= o) ? s[t - o] : 0;
            __syncthreads();
            s[t] += x; __syncthreads();
        }
        int excl = s[t] - v + carry;
        if (i < nblk) hist[b * nblk + i] = excl;
        if (t == 255) carry += s[255];
        __syncthreads();
    }
}

// B5: per-chunk LDS counting sort -> coalesced bucket-sorted writes of packed records
__global__ __launch_bounds__(256) void edge_part(const int* __restrict__ src,
                                                 const int* __restrict__ dst,
                                                 const int* __restrict__ hist,  // block bases
                                                 int* __restrict__ part,
                                                 int E, int nblk, int nbuck) {
    __shared__ int hcnt[128];
    __shared__ int lstart[128];
    __shared__ int cur[128];
    __shared__ int gbase[128];
    __shared__ int ssc[128];
    __shared__ int sdst[EPB];  // 16 KB
    __shared__ int ssrc[EPB];  // 16 KB
    int t = threadIdx.x, blk = blockIdx.x;
    int e0 = blk * EPB;
    int cnt = E - e0; if (cnt > EPB) cnt = EPB;
    if (t < nbuck) { hcnt[t] = 0; gbase[t] = hist[t * nblk + blk]; }
    __syncthreads();
    int myd[EPB / 256], mys[EPB / 256];
#pragma unroll
    for (int it = 0; it < EPB / 256; it++) {
        int i = it * 256 + t;
        if (i < cnt) {
            myd[it] = dst[e0 + i];
            mys[it] = src[e0 + i];
            atomicAdd(&hcnt[myd[it] >> BUCKET_BITS], 1);
        }
    }
    __syncthreads();
    // exclusive scan over buckets
    if (t < 128) ssc[t] = (t < nbuck) ? hcnt[t] : 0;
    __syncthreads();
#pragma unroll
    for (int o = 1; o < 128; o <<= 1) {
        int x = 0;
        if (t < 128 && t >= o) x = ssc[t - o];
        __syncthreads();
        if (t < 128) ssc[t] += x;
        __syncthreads();
    }
    if (t < nbuck) { lstart[t] = ssc[t] - hcnt[t]; cur[t] = 0; }
    __syncthreads();
    // scatter into LDS, sorted by bucket
#pragma unroll
    for (int it = 0; it < EPB / 256; it++) {
        int i = it * 256 + t;
        if (i < cnt) {
            int b = myd[it] >> BUCKET_BITS;
            int p = lstart[b] + atomicAdd(&cur[b], 1);
            sdst[p] = myd[it];
            ssrc[p] = mys[it];
        }
    }
    __syncthreads();
    // coalesced write-out: record = (local_dst << 17) | src
    for (int i = t; i < cnt; i += 256) {
        int d = sdst[i], s = ssrc[i];
        int b = d >> BUCKET_BITS;
        part[gbase[b] + (i - lstart[b])] = ((d & (BUCKET_SIZE - 1)) << 17) | s;
    }
}

// B6: per-bucket finalize: deg/off per node + dst-sorted csr_src
__global__ __launch_bounds__(256) void csr_finalize(const int* __restrict__ part,
                                                    const int* __restrict__ bucketBase,
                                                    int* __restrict__ off_,
                                                    int* __restrict__ deg_,
                                                    int* __restrict__ csr_src,
                                                    int N) {
    __shared__ int cur[BUCKET_SIZE];   // 4 KB
    __shared__ int h[BUCKET_SIZE];     // 4 KB
    __shared__ int tsum[256];
    int b = blockIdx.x, t = threadIdx.x;
    int lo = bucketBase[b], hi = bucketBase[b + 1];
    int n0 = b * BUCKET_SIZE;
    for (int i = t; i < BUCKET_SIZE; i += 256) h[i] = 0;
    __syncthreads();
    for (int i = lo + t; i < hi; i += 256) atomicAdd(&h[part[i] >> 17], 1);
    __syncthreads();
    // scan 1024 bins: thread t owns bins [4t, 4t+4)
    int a0 = h[4 * t], a1 = h[4 * t + 1], a2 = h[4 * t + 2], a3 = h[4 * t + 3];
    int ts = a0 + a1 + a2 + a3;
    tsum[t] = ts;
    __syncthreads();
#pragma unroll
    for (int o = 1; o < 256; o <<= 1) {
        int x = (t >= o) ? tsum[t - o] : 0;
        __syncthreads();
        tsum[t] += x;
        __syncthreads();
    }
    int st0 = tsum[t] - ts;
    int st1 = st0 + a0, st2 = st1 + a1, st3 = st2 + a2;
    cur[4 * t] = st0; cur[4 * t + 1] = st1; cur[4 * t + 2] = st2; cur[4 * t + 3] = st3;
    int node = n0 + 4 * t;
    if (node < N)     { off_[node] = lo + st0;     deg_[node] = a0; }
    if (node + 1 < N) { off_[node + 1] = lo + st1; deg_[node + 1] = a1; }
    if (node + 2 < N) { off_[node + 2] = lo + st2; deg_[node + 2] = a2; }
    if (node + 3 < N) { off_[node + 3] = lo + st3; deg_[node + 3] = a3; }
    __syncthreads();
    // scatter srcs into node-sorted order within the bucket region
    for (int i = lo + t; i < hi; i += 256) {
        int rec = part[i];
        int p = atomicAdd(&cur[rec >> 17], 1);
        csr_src[lo + p] = rec & 0x1FFFF;
    }
}

// ================= layer GEMM =================
// [N,128]bf16 @ [128,256]bf16 -> xr[N,128]bf16 (cols 0..127), acc[N,128]f32 = cols 128..255 + bias
__global__ __launch_bounds__(256) void gemm_layer(const unsigned short* __restrict__ Abf,
                                                  const unsigned short* __restrict__ Bsw,
                                                  const float* __restrict__ bias,
                                                  unsigned short* __restrict__ xr,
                                                  float* __restrict__ accbuf, int N) {
    int wid = blockIdx.x * 4 + (threadIdx.x >> 6);
    int L = threadIdx.x & 63;
    int r0 = wid * 16;
    if (r0 >= N) return;
    int arow = r0 + (L & 15);
    const bf16x8* Aptr = (const bf16x8*)(Abf + (size_t)arow * 128 + ((L >> 4) * 8));
    const bf16x8* Bptr = ((const bf16x8*)Bsw) + L;
    f32x4 acc[16];
#pragma unroll
    for (int i = 0; i < 16; i++) acc[i] = (f32x4){0.f, 0.f, 0.f, 0.f};
#pragma unroll
    for (int kt = 0; kt < 4; kt++) {
        bf16x8 a = Aptr[kt * 4];
#pragma unroll
        for (int ct = 0; ct < 16; ct++) {
            bf16x8 b = Bptr[(kt * 16 + ct) * 64];
            acc[ct] = __builtin_amdgcn_mfma_f32_16x16x32_bf16(a, b, acc[ct], 0, 0, 0);
        }
    }
    int rbase = r0 + (L >> 4) * 4;
    int cl = L & 15;
#pragma unroll
    for (int ct = 0; ct < 16; ct++) {
        int col = ct * 16 + cl;
#pragma unroll
        for (int r = 0; r < 4; r++) {
            int row = rbase + r;
            float v = acc[ct][r];
            if (col < 128)
                xr[(size_t)row * 128 + col] = f2bf(v);
            else
                accbuf[(size_t)row * 128 + (col - 128)] = v + bias[col - 128];
        }
    }
}

// ================= gather-aggregate + relu + bf16 convert =================
// one wave per node; lane L owns features 2L, 2L+1 (high-TLP latency hiding)
__global__ __launch_bounds__(256) void agg_relu_cvt(const unsigned short* __restrict__ xr,
                                                    const float* __restrict__ acc,
                                                    const int* __restrict__ off_,
                                                    const int* __restrict__ deg,
                                                    const int* __restrict__ csr_src,
                                                    unsigned short* __restrict__ out, int N) {
    int node = blockIdx.x * 4 + (threadIdx.x >> 6);
    if (node >= N) return;
    int L = threadIdx.x & 63;
    int o = off_[node];
    int d = deg[node];
    float s0 = 0.f, s1 = 0.f;
    int k = 0;
    while (k < d) {
        int chunk = (d - k < 64) ? (d - k) : 64;
        int id = 0;
        if (L < chunk) id = csr_src[o + k + L];
#pragma unroll 4
        for (int j = 0; j < chunk; j++) {
            int s = __shfl(id, j, 64);
            unsigned int packed = *(const unsigned int*)(xr + (size_t)s * 128 + L * 2);
            s0 += bf2f((unsigned short)(packed & 0xFFFF));
            s1 += bf2f((unsigned short)(packed >> 16));
        }
        k += chunk;
    }
    float2 a = *(const float2*)(acc + (size_t)node * 128 + L * 2);
    float r0 = fmaxf(a.x + s0, 0.f);
    float r1 = fmaxf(a.y + s1, 0.f);
    unsigned int op = ((unsigned)f2bf(r1) << 16) | (unsigned)f2bf(r0);
    *(unsigned int*)(out + (size_t)node * 128 + L * 2) = op;
}

// ================= final GEMM + log_softmax =================
__global__ __launch_bounds__(256) void gemm_final(const unsigned short* __restrict__ x1bf,
                                                  const unsigned short* __restrict__ x2bf,
                                                  const unsigned short* __restrict__ Bsw,
                                                  const float* __restrict__ blin,
                                                  float* __restrict__ logits, int N) {
    int wid = blockIdx.x * 4 + (threadIdx.x >> 6);
    int L = threadIdx.x & 63;
    int r0 = wid * 16;
    if (r0 >= N) return;
    int arow = r0 + (L & 15);
    f32x4 acc[3];
#pragma unroll
    for (int i = 0; i < 3; i++) acc[i] = (f32x4){0.f, 0.f, 0.f, 0.f};
#pragma unroll
    for (int kt = 0; kt < 8; kt++) {
        const unsigned short* Ab = (kt < 4) ? x1bf : x2bf;
        int kk = (kt & 3) * 32 + ((L >> 4) * 8);
        bf16x8 a = *((const bf16x8*)(Ab + (size_t)arow * 128 + kk));
#pragma unroll
        for (int ct = 0; ct < 3; ct++) {
            bf16x8 b = ((const bf16x8*)Bsw)[(kt * 3 + ct) * 64 + L];
            acc[ct] = __builtin_amdgcn_mfma_f32_16x16x32_bf16(a, b, acc[ct], 0, 0, 0);
        }
    }
    int rbase = r0 + (L >> 4) * 4;
    int cl = L & 15;
#pragma unroll
    for (int ct = 0; ct < 3; ct++) {
        int col = ct * 16 + cl;
        if (col < 40) {
#pragma unroll
            for (int r = 0; r < 4; r++) {
                logits[(size_t)(rbase + r) * 40 + col] = acc[ct][r] + blin[col];
            }
        }
    }
}

__global__ __launch_bounds__(256) void log_softmax_k(const float* __restrict__ logits,
                                                     float* __restrict__ out, int N) {
    int node = blockIdx.x * 4 + (threadIdx.x >> 6);
    if (node >= N) return;
    int L = threadIdx.x & 63;
    float v = (L < 40) ? logits[(size_t)node * 40 + L] : -__builtin_inff();
    float m = v;
#pragma unroll
    for (int off = 32; off >= 1; off >>= 1) m = fmaxf(m, __shfl_xor(m, off, 64));
    float e = (L < 40) ? __expf(v - m) : 0.f;
    float s = e;
#pragma unroll
    for (int off = 32; off >= 1; off >>= 1) s += __shfl_xor(s, off, 64);
    if (L < 40) out[(size_t)node * 40 + L] = v - m - __logf(s);
}

extern "C" void kernel_launch(void* const* d_in, const int* in_sizes, int n_in,
                              void* d_out, int out_size, void* d_ws, size_t ws_size,
                              hipStream_t stream) {
    const float* x      = (const float*)d_in[0];
    const int*   edge   = (const int*)d_in[1];
    const float* Wrel1  = (const float*)d_in[2];
    const float* brel1  = (const float*)d_in[3];
    const float* Wroot1 = (const float*)d_in[4];
    const float* Wrel2  = (const float*)d_in[5];
    const float* brel2  = (const float*)d_in[6];
    const float* Wroot2 = (const float*)d_in[7];
    const float* Wlin   = (const float*)d_in[8];
    const float* blin   = (const float*)d_in[9];

    const int N = in_sizes[0] / 128;
    const int E = in_sizes[1] / 2;
    const int* src = edge;
    const int* dst = edge + E;

    const int nblk  = (E + EPB - 1) / EPB;                    // 391
    const int nbuck = (N + BUCKET_SIZE - 1) / BUCKET_SIZE;    // 98

    char* ws = (char*)d_ws;
    size_t off = 0;
    auto alloc = [&](size_t bytes) -> void* {
        void* p = ws + off;
        off += (bytes + 255) & ~(size_t)255;
        return p;
    };
    unsigned short* xbf  = (unsigned short*)alloc((size_t)N * 128 * 2);  // reused as x2bf
    unsigned short* x1bf = (unsigned short*)alloc((size_t)N * 128 * 2);
    unsigned short* xr   = (unsigned short*)alloc((size_t)N * 128 * 2);
    float* acc1          = (float*)alloc((size_t)N * 128 * 4);           // reused as logits
    float* acc2          = (float*)alloc((size_t)N * 128 * 4);
    unsigned short* bsw1 = (unsigned short*)alloc(32768 * 2);
    unsigned short* bsw2 = (unsigned short*)alloc(32768 * 2);
    unsigned short* bswL = (unsigned short*)alloc(12288 * 2);
    int* hist       = (int*)alloc((size_t)nbuck * nblk * 4);
    int* bucketTot  = (int*)alloc((size_t)nbuck * 4);
    int* bucketBase = (int*)alloc((size_t)(nbuck + 1) * 4);
    int* part       = (int*)alloc((size_t)E * 4);
    int* csr_src    = (int*)alloc((size_t)E * 4);
    int* off_       = (int*)alloc((size_t)N * 4);
    int* deg_       = (int*)alloc((size_t)N * 4);
    unsigned short* x2bf = xbf;
    float* logits        = acc1;

    const int n4 = (N * 128) / 4;
    const int cvtBlocks = (n4 + 255) / 256;
    const int rowTiles = (N + 15) / 16;
    const int gemmBlocks = (rowTiles + 3) / 4;
    const int nodeBlocks = (N + 3) / 4;

    // weight swizzles + input convert
    build_bsw<<<128, 256, 0, stream>>>(Wrel1, Wroot1, bsw1);
    build_bsw<<<128, 256, 0, stream>>>(Wrel2, Wroot2, bsw2);
    build_bswL<<<48, 256, 0, stream>>>(Wlin, bswL, 12288);
    cvt_bf16<<<cvtBlocks, 256, 0, stream>>>(x, xbf, n4);

    // atomic-free CSR build (once; shared by both layers)
    edge_hist<<<nblk, 256, 0, stream>>>(dst, hist, E, nblk, nbuck);
    bucket_total<<<nbuck, 256, 0, stream>>>(hist, bucketTot, nblk);
    bucket_scan<<<1, 128, 0, stream>>>(bucketTot, bucketBase, nbuck);
    block_scan<<<nbuck, 256, 0, stream>>>(hist, bucketBase, nblk);
    edge_part<<<nblk, 256, 0, stream>>>(src, dst, hist, part, E, nblk, nbuck);
    csr_finalize<<<nbuck, 256, 0, stream>>>(part, bucketBase, off_, deg_, csr_src, N);

    // layer 1
    gemm_layer<<<gemmBlocks, 256, 0, stream>>>(xbf, bsw1, brel1, xr, acc1, N);
    agg_relu_cvt<<<nodeBlocks, 256, 0, stream>>>(xr, acc1, off_, deg_, csr_src, x1bf, N);

    // layer 2
    gemm_layer<<<gemmBlocks, 256, 0, stream>>>(x1bf, bsw2, brel2, xr, acc2, N);
    agg_relu_cvt<<<nodeBlocks, 256, 0, stream>>>(xr, acc2, off_, deg_, csr_src, x2bf, N);

    // classifier + log_softmax
    gemm_final<<<gemmBlocks, 256, 0, stream>>>(x1bf, x2bf, bswL, blin, logits, N);
    log_softmax_k<<<nodeBlocks, 256, 0, stream>>>(logits, (float*)d_out, N);
}

// Round 5
// 410.709 us; speedup vs baseline: 7.3486x; 1.2106x over previous
//
#include <hip/hip_runtime.h>
#include <hip/hip_bf16.h>

typedef __attribute__((ext_vector_type(8))) short bf16x8;
typedef __attribute__((ext_vector_type(4))) float f32x4;

#define EPB 4096          // edges per partition block
#define BUCKET_BITS 10
#define BUCKET_SIZE 1024  // nodes per bucket

static __device__ __forceinline__ unsigned short f2bf(float f) {
    union { float f; unsigned u; } v; v.f = f;
    unsigned r = v.u + 0x7FFF + ((v.u >> 16) & 1);
    return (unsigned short)(r >> 16);
}
static __device__ __forceinline__ float bf2f(unsigned short h) {
    union { unsigned u; float f; } v; v.u = ((unsigned)h) << 16;
    return v.f;
}

// ---- convert f32 -> bf16 (4 elems/thread) ----
__global__ __launch_bounds__(256) void cvt_bf16(const float* __restrict__ x,
                                                unsigned short* __restrict__ out, int n4) {
    int i = blockIdx.x * 256 + threadIdx.x;
    if (i >= n4) return;
    float4 v = ((const float4*)x)[i];
    ushort4 o;
    o.x = f2bf(v.x); o.y = f2bf(v.y); o.z = f2bf(v.z); o.w = f2bf(v.w);
    ((ushort4*)out)[i] = o;
}

// ---- build swizzled B = [W_rel | W_root] in MFMA B-fragment order ----
__global__ __launch_bounds__(256) void build_bsw(const float* __restrict__ Wrel,
                                                 const float* __restrict__ Wroot,
                                                 unsigned short* __restrict__ bsw) {
    int idx = blockIdx.x * 256 + threadIdx.x;  // 32768 total
    int j = idx & 7, L = (idx >> 3) & 63, ct = (idx >> 9) & 15, kt = idx >> 13;
    int k = kt * 32 + ((L >> 4) * 8) + j;
    int c = ct * 16 + (L & 15);
    float v = (c < 128) ? Wrel[k * 128 + c] : Wroot[k * 128 + (c - 128)];
    bsw[idx] = f2bf(v);
}

// ---- build swizzled W_lin [256,40] padded to 48 cols ----
__global__ __launch_bounds__(256) void build_bswL(const float* __restrict__ Wlin,
                                                  unsigned short* __restrict__ bsw, int total) {
    int idx = blockIdx.x * 256 + threadIdx.x;  // 12288 total
    if (idx >= total) return;
    int t = idx;
    int j = t & 7; t >>= 3;
    int L = t & 63; t >>= 6;
    int ct = t % 3;
    int kt = t / 3;
    int k = kt * 32 + ((L >> 4) * 8) + j;
    int c = ct * 16 + (L & 15);
    float v = (c < 40) ? Wlin[k * 40 + c] : 0.f;
    bsw[idx] = f2bf(v);
}

// ================= atomic-free CSR build =================

// B1: per-block histogram over buckets (LDS atomics only)
__global__ __launch_bounds__(256) void edge_hist(const int* __restrict__ dst,
                                                 int* __restrict__ hist,  // [nbuck][nblk]
                                                 int E, int nblk, int nbuck) {
    __shared__ int h[128];
    int t = threadIdx.x, blk = blockIdx.x;
    if (t < nbuck) h[t] = 0;
    __syncthreads();
    int e0 = blk * EPB;
#pragma unroll
    for (int it = 0; it < EPB / 256; it++) {
        int e = e0 + it * 256 + t;
        if (e < E) atomicAdd(&h[dst[e] >> BUCKET_BITS], 1);
    }
    __syncthreads();
    if (t < nbuck) hist[t * nblk + blk] = h[t];
}

// B2: bucket totals
__global__ __launch_bounds__(256) void bucket_total(const int* __restrict__ hist,
                                                    int* __restrict__ total, int nblk) {
    __shared__ int s[256];
    int b = blockIdx.x, t = threadIdx.x;
    int v = 0;
    for (int i = t; i < nblk; i += 256) v += hist[b * nblk + i];
    s[t] = v; __syncthreads();
#pragma unroll
    for (int o = 128; o >= 1; o >>= 1) {
        if (t < o) s[t] += s[t + o];
        __syncthreads();
    }
    if (t == 0) total[b] = s[0];
}

// B3: exclusive scan of bucket totals (single block, nbuck <= 128)
__global__ __launch_bounds__(128) void bucket_scan(const int* __restrict__ total,
                                                   int* __restrict__ base, int nbuck) {
    __shared__ int s[128];
    int t = threadIdx.x;
    int v = (t < nbuck) ? total[t] : 0;
    s[t] = v; __syncthreads();
#pragma unroll
    for (int o = 1; o < 128; o <<= 1) {
        int x = (t >= o) ? s[t - o] : 0;
        __syncthreads();
        s[t] += x; __syncthreads();
    }
    if (t < nbuck) base[t] = s[t] - v;
    if (t == 127) base[nbuck] = s[127];
}

// B4: per-bucket scan over blocks: hist[b][blk] -> global slot base (in place)
__global__ __launch_bounds__(256) void block_scan(int* __restrict__ hist,
                                                  const int* __restrict__ base, int nblk) {
    __shared__ int s[256];
    __shared__ int carry;
    int b = blockIdx.x, t = threadIdx.x;
    if (t == 0) carry = base[b];
    __syncthreads();
    for (int start = 0; start < nblk; start += 256) {
        int i = start + t;
        int v = (i < nblk) ? hist[b * nblk + i] : 0;
        s[t] = v; __syncthreads();
#pragma unroll
        for (int o = 1; o < 256; o <<= 1) {
            int x = (t >= o) ? s[t - o] : 0;
            __syncthreads();
            s[t] += x; __syncthreads();
        }
        int excl = s[t] - v + carry;
        if (i < nblk) hist[b * nblk + i] = excl;
        if (t == 255) carry += s[255];
        __syncthreads();
    }
}

// B5: per-chunk LDS counting sort -> coalesced bucket-sorted writes of packed records
__global__ __launch_bounds__(256) void edge_part(const int* __restrict__ src,
                                                 const int* __restrict__ dst,
                                                 const int* __restrict__ hist,  // block bases
                                                 int* __restrict__ part,
                                                 int E, int nblk, int nbuck) {
    __shared__ int hcnt[128];
    __shared__ int lstart[128];
    __shared__ int cur[128];
    __shared__ int gbase[128];
    __shared__ int ssc[128];
    __shared__ int sdst[EPB];  // 16 KB
    __shared__ int ssrc[EPB];  // 16 KB
    int t = threadIdx.x, blk = blockIdx.x;
    int e0 = blk * EPB;
    int cnt = E - e0; if (cnt > EPB) cnt = EPB;
    if (t < nbuck) { hcnt[t] = 0; gbase[t] = hist[t * nblk + blk]; }
    __syncthreads();
    int myd[EPB / 256], mys[EPB / 256];
#pragma unroll
    for (int it = 0; it < EPB / 256; it++) {
        int i = it * 256 + t;
        if (i < cnt) {
            myd[it] = dst[e0 + i];
            mys[it] = src[e0 + i];
            atomicAdd(&hcnt[myd[it] >> BUCKET_BITS], 1);
        }
    }
    __syncthreads();
    if (t < 128) ssc[t] = (t < nbuck) ? hcnt[t] : 0;
    __syncthreads();
#pragma unroll
    for (int o = 1; o < 128; o <<= 1) {
        int x = 0;
        if (t < 128 && t >= o) x = ssc[t - o];
        __syncthreads();
        if (t < 128) ssc[t] += x;
        __syncthreads();
    }
    if (t < nbuck) { lstart[t] = ssc[t] - hcnt[t]; cur[t] = 0; }
    __syncthreads();
#pragma unroll
    for (int it = 0; it < EPB / 256; it++) {
        int i = it * 256 + t;
        if (i < cnt) {
            int b = myd[it] >> BUCKET_BITS;
            int p = lstart[b] + atomicAdd(&cur[b], 1);
            sdst[p] = myd[it];
            ssrc[p] = mys[it];
        }
    }
    __syncthreads();
    for (int i = t; i < cnt; i += 256) {
        int d = sdst[i], s = ssrc[i];
        int b = d >> BUCKET_BITS;
        part[gbase[b] + (i - lstart[b])] = ((d & (BUCKET_SIZE - 1)) << 17) | s;
    }
}

// B6: per-bucket finalize: deg/off per node + dst-sorted csr_src
__global__ __launch_bounds__(256) void csr_finalize(const int* __restrict__ part,
                                                    const int* __restrict__ bucketBase,
                                                    int* __restrict__ off_,
                                                    int* __restrict__ deg_,
                                                    int* __restrict__ csr_src,
                                                    int N) {
    __shared__ int cur[BUCKET_SIZE];   // 4 KB
    __shared__ int h[BUCKET_SIZE];     // 4 KB
    __shared__ int tsum[256];
    int b = blockIdx.x, t = threadIdx.x;
    int lo = bucketBase[b], hi = bucketBase[b + 1];
    int n0 = b * BUCKET_SIZE;
    for (int i = t; i < BUCKET_SIZE; i += 256) h[i] = 0;
    __syncthreads();
    for (int i = lo + t; i < hi; i += 256) atomicAdd(&h[part[i] >> 17], 1);
    __syncthreads();
    int a0 = h[4 * t], a1 = h[4 * t + 1], a2 = h[4 * t + 2], a3 = h[4 * t + 3];
    int ts = a0 + a1 + a2 + a3;
    tsum[t] = ts;
    __syncthreads();
#pragma unroll
    for (int o = 1; o < 256; o <<= 1) {
        int x = (t >= o) ? tsum[t - o] : 0;
        __syncthreads();
        tsum[t] += x;
        __syncthreads();
    }
    int st0 = tsum[t] - ts;
    int st1 = st0 + a0, st2 = st1 + a1, st3 = st2 + a2;
    cur[4 * t] = st0; cur[4 * t + 1] = st1; cur[4 * t + 2] = st2; cur[4 * t + 3] = st3;
    int node = n0 + 4 * t;
    if (node < N)     { off_[node] = lo + st0;     deg_[node] = a0; }
    if (node + 1 < N) { off_[node + 1] = lo + st1; deg_[node + 1] = a1; }
    if (node + 2 < N) { off_[node + 2] = lo + st2; deg_[node + 2] = a2; }
    if (node + 3 < N) { off_[node + 3] = lo + st3; deg_[node + 3] = a3; }
    __syncthreads();
    for (int i = lo + t; i < hi; i += 256) {
        int rec = part[i];
        int p = atomicAdd(&cur[rec >> 17], 1);
        csr_src[lo + p] = rec & 0x1FFFF;
    }
}

// ================= layer GEMM =================
__global__ __launch_bounds__(256) void gemm_layer(const unsigned short* __restrict__ Abf,
                                                  const unsigned short* __restrict__ Bsw,
                                                  const float* __restrict__ bias,
                                                  unsigned short* __restrict__ xr,
                                                  float* __restrict__ accbuf, int N) {
    int wid = blockIdx.x * 4 + (threadIdx.x >> 6);
    int L = threadIdx.x & 63;
    int r0 = wid * 16;
    if (r0 >= N) return;
    int arow = r0 + (L & 15);
    const bf16x8* Aptr = (const bf16x8*)(Abf + (size_t)arow * 128 + ((L >> 4) * 8));
    const bf16x8* Bptr = ((const bf16x8*)Bsw) + L;
    f32x4 acc[16];
#pragma unroll
    for (int i = 0; i < 16; i++) acc[i] = (f32x4){0.f, 0.f, 0.f, 0.f};
#pragma unroll
    for (int kt = 0; kt < 4; kt++) {
        bf16x8 a = Aptr[kt * 4];
#pragma unroll
        for (int ct = 0; ct < 16; ct++) {
            bf16x8 b = Bptr[(kt * 16 + ct) * 64];
            acc[ct] = __builtin_amdgcn_mfma_f32_16x16x32_bf16(a, b, acc[ct], 0, 0, 0);
        }
    }
    int rbase = r0 + (L >> 4) * 4;
    int cl = L & 15;
#pragma unroll
    for (int ct = 0; ct < 16; ct++) {
        int col = ct * 16 + cl;
#pragma unroll
        for (int r = 0; r < 4; r++) {
            int row = rbase + r;
            float v = acc[ct][r];
            if (col < 128)
                xr[(size_t)row * 128 + col] = f2bf(v);
            else
                accbuf[(size_t)row * 128 + (col - 128)] = v + bias[col - 128];
        }
    }
}

// ================= gather-aggregate + relu + bf16 convert =================
// one wave per node; 4 edges per load instruction (dwordx4, 1 KiB/instr).
// lane L = (g=L>>4: edge slot, f=L&15: feature-8 group)
__global__ __launch_bounds__(256) void agg_relu_cvt(const unsigned short* __restrict__ xr,
                                                    const float* __restrict__ acc,
                                                    const int* __restrict__ off_,
                                                    const int* __restrict__ deg,
                                                    const int* __restrict__ csr_src,
                                                    unsigned short* __restrict__ out, int N) {
    int node = blockIdx.x * 4 + (threadIdx.x >> 6);
    if (node >= N) return;
    int L = threadIdx.x & 63;
    int g = L >> 4;
    int f = L & 15;
    int o = off_[node];
    int d = deg[node];
    float af[8];
#pragma unroll
    for (int i = 0; i < 8; i++) af[i] = 0.f;

    for (int k = 0; k < d; k += 64) {
        int chunk = (d - k < 64) ? (d - k) : 64;
        int id = (L < chunk) ? csr_src[o + k + L] : 0;
        int full = chunk & ~3;
#pragma unroll 4
        for (int j = 0; j < full; j += 4) {
            int s = __shfl(id, j + g, 64);
            bf16x8 p = *(const bf16x8*)(xr + (size_t)s * 128 + f * 8);
#pragma unroll
            for (int i = 0; i < 8; i++) af[i] += bf2f((unsigned short)p[i]);
        }
        if (full < chunk) {
            int sl = full + g;
            int s = __shfl(id, (sl < chunk) ? sl : 0, 64);
            if (sl < chunk) {
                bf16x8 p = *(const bf16x8*)(xr + (size_t)s * 128 + f * 8);
#pragma unroll
                for (int i = 0; i < 8; i++) af[i] += bf2f((unsigned short)p[i]);
            }
        }
    }
    // cross-edge-slot reduction: sum over lanes {f, 16+f, 32+f, 48+f}
#pragma unroll
    for (int i = 0; i < 8; i++) af[i] += __shfl_xor(af[i], 16, 64);
#pragma unroll
    for (int i = 0; i < 8; i++) af[i] += __shfl_xor(af[i], 32, 64);

    if (g == 0) {
        const float* ap = acc + (size_t)node * 128 + f * 8;
        float4 a0 = *(const float4*)ap;
        float4 a1 = *(const float4*)(ap + 4);
        float r0 = fmaxf(a0.x + af[0], 0.f), r1 = fmaxf(a0.y + af[1], 0.f);
        float r2 = fmaxf(a0.z + af[2], 0.f), r3 = fmaxf(a0.w + af[3], 0.f);
        float r4 = fmaxf(a1.x + af[4], 0.f), r5 = fmaxf(a1.y + af[5], 0.f);
        float r6 = fmaxf(a1.z + af[6], 0.f), r7 = fmaxf(a1.w + af[7], 0.f);
        uint4 wv;
        wv.x = ((unsigned)f2bf(r1) << 16) | f2bf(r0);
        wv.y = ((unsigned)f2bf(r3) << 16) | f2bf(r2);
        wv.z = ((unsigned)f2bf(r5) << 16) | f2bf(r4);
        wv.w = ((unsigned)f2bf(r7) << 16) | f2bf(r6);
        *(uint4*)(out + (size_t)node * 128 + f * 8) = wv;
    }
}

// ================= final GEMM + log_softmax =================
__global__ __launch_bounds__(256) void gemm_final(const unsigned short* __restrict__ x1bf,
                                                  const unsigned short* __restrict__ x2bf,
                                                  const unsigned short* __restrict__ Bsw,
                                                  const float* __restrict__ blin,
                                                  float* __restrict__ logits, int N) {
    int wid = blockIdx.x * 4 + (threadIdx.x >> 6);
    int L = threadIdx.x & 63;
    int r0 = wid * 16;
    if (r0 >= N) return;
    int arow = r0 + (L & 15);
    f32x4 acc[3];
#pragma unroll
    for (int i = 0; i < 3; i++) acc[i] = (f32x4){0.f, 0.f, 0.f, 0.f};
#pragma unroll
    for (int kt = 0; kt < 8; kt++) {
        const unsigned short* Ab = (kt < 4) ? x1bf : x2bf;
        int kk = (kt & 3) * 32 + ((L >> 4) * 8);
        bf16x8 a = *((const bf16x8*)(Ab + (size_t)arow * 128 + kk));
#pragma unroll
        for (int ct = 0; ct < 3; ct++) {
            bf16x8 b = ((const bf16x8*)Bsw)[(kt * 3 + ct) * 64 + L];
            acc[ct] = __builtin_amdgcn_mfma_f32_16x16x32_bf16(a, b, acc[ct], 0, 0, 0);
        }
    }
    int rbase = r0 + (L >> 4) * 4;
    int cl = L & 15;
#pragma unroll
    for (int ct = 0; ct < 3; ct++) {
        int col = ct * 16 + cl;
        if (col < 40) {
#pragma unroll
            for (int r = 0; r < 4; r++) {
                logits[(size_t)(rbase + r) * 40 + col] = acc[ct][r] + blin[col];
            }
        }
    }
}

__global__ __launch_bounds__(256) void log_softmax_k(const float* __restrict__ logits,
                                                     float* __restrict__ out, int N) {
    int node = blockIdx.x * 4 + (threadIdx.x >> 6);
    if (node >= N) return;
    int L = threadIdx.x & 63;
    float v = (L < 40) ? logits[(size_t)node * 40 + L] : -__builtin_inff();
    float m = v;
#pragma unroll
    for (int off = 32; off >= 1; off >>= 1) m = fmaxf(m, __shfl_xor(m, off, 64));
    float e = (L < 40) ? __expf(v - m) : 0.f;
    float s = e;
#pragma unroll
    for (int off = 32; off >= 1; off >>= 1) s += __shfl_xor(s, off, 64);
    if (L < 40) out[(size_t)node * 40 + L] = v - m - __logf(s);
}

extern "C" void kernel_launch(void* const* d_in, const int* in_sizes, int n_in,
                              void* d_out, int out_size, void* d_ws, size_t ws_size,
                              hipStream_t stream) {
    const float* x      = (const float*)d_in[0];
    const int*   edge   = (const int*)d_in[1];
    const float* Wrel1  = (const float*)d_in[2];
    const float* brel1  = (const float*)d_in[3];
    const float* Wroot1 = (const float*)d_in[4];
    const float* Wrel2  = (const float*)d_in[5];
    const float* brel2  = (const float*)d_in[6];
    const float* Wroot2 = (const float*)d_in[7];
    const float* Wlin   = (const float*)d_in[8];
    const float* blin   = (const float*)d_in[9];

    const int N = in_sizes[0] / 128;
    const int E = in_sizes[1] / 2;
    const int* src = edge;
    const int* dst = edge + E;

    const int nblk  = (E + EPB - 1) / EPB;                    // 391
    const int nbuck = (N + BUCKET_SIZE - 1) / BUCKET_SIZE;    // 98

    char* ws = (char*)d_ws;
    size_t off = 0;
    auto alloc = [&](size_t bytes) -> void* {
        void* p = ws + off;
        off += (bytes + 255) & ~(size_t)255;
        return p;
    };
    unsigned short* xbf  = (unsigned short*)alloc((size_t)N * 128 * 2);  // reused as x2bf
    unsigned short* x1bf = (unsigned short*)alloc((size_t)N * 128 * 2);
    unsigned short* xr   = (unsigned short*)alloc((size_t)N * 128 * 2);
    float* acc1          = (float*)alloc((size_t)N * 128 * 4);           // reused as logits
    float* acc2          = (float*)alloc((size_t)N * 128 * 4);
    unsigned short* bsw1 = (unsigned short*)alloc(32768 * 2);
    unsigned short* bsw2 = (unsigned short*)alloc(32768 * 2);
    unsigned short* bswL = (unsigned short*)alloc(12288 * 2);
    int* hist       = (int*)alloc((size_t)nbuck * nblk * 4);
    int* bucketTot  = (int*)alloc((size_t)nbuck * 4);
    int* bucketBase = (int*)alloc((size_t)(nbuck + 1) * 4);
    int* part       = (int*)alloc((size_t)E * 4);
    int* csr_src    = (int*)alloc((size_t)E * 4);
    int* off_       = (int*)alloc((size_t)N * 4);
    int* deg_       = (int*)alloc((size_t)N * 4);
    unsigned short* x2bf = xbf;
    float* logits        = acc1;

    const int n4 = (N * 128) / 4;
    const int cvtBlocks = (n4 + 255) / 256;
    const int rowTiles = (N + 15) / 16;
    const int gemmBlocks = (rowTiles + 3) / 4;
    const int nodeBlocks = (N + 3) / 4;

    // weight swizzles + input convert
    build_bsw<<<128, 256, 0, stream>>>(Wrel1, Wroot1, bsw1);
    build_bsw<<<128, 256, 0, stream>>>(Wrel2, Wroot2, bsw2);
    build_bswL<<<48, 256, 0, stream>>>(Wlin, bswL, 12288);
    cvt_bf16<<<cvtBlocks, 256, 0, stream>>>(x, xbf, n4);

    // atomic-free CSR build (once; shared by both layers)
    edge_hist<<<nblk, 256, 0, stream>>>(dst, hist, E, nblk, nbuck);
    bucket_total<<<nbuck, 256, 0, stream>>>(hist, bucketTot, nblk);
    bucket_scan<<<1, 128, 0, stream>>>(bucketTot, bucketBase, nbuck);
    block_scan<<<nbuck, 256, 0, stream>>>(hist, bucketBase, nblk);
    edge_part<<<nblk, 256, 0, stream>>>(src, dst, hist, part, E, nblk, nbuck);
    csr_finalize<<<nbuck, 256, 0, stream>>>(part, bucketBase, off_, deg_, csr_src, N);

    // layer 1
    gemm_layer<<<gemmBlocks, 256, 0, stream>>>(xbf, bsw1, brel1, xr, acc1, N);
    agg_relu_cvt<<<nodeBlocks, 256, 0, stream>>>(xr, acc1, off_, deg_, csr_src, x1bf, N);

    // layer 2
    gemm_layer<<<gemmBlocks, 256, 0, stream>>>(x1bf, bsw2, brel2, xr, acc2, N);
    agg_relu_cvt<<<nodeBlocks, 256, 0, stream>>>(xr, acc2, off_, deg_, csr_src, x2bf, N);

    // classifier + log_softmax
    gemm_final<<<gemmBlocks, 256, 0, stream>>>(x1bf, x2bf, bswL, blin, logits, N);
    log_softmax_k<<<nodeBlocks, 256, 0, stream>>>(logits, (float*)d_out, N);
}

// Round 6
// 407.991 us; speedup vs baseline: 7.3975x; 1.0067x over previous
//
#include <hip/hip_runtime.h>
#include <hip/hip_bf16.h>

typedef __attribute__((ext_vector_type(8))) short bf16x8;
typedef __attribute__((ext_vector_type(4))) float f32x4;

#define EPB 4096          // edges per partition block
#define BUCKET_BITS 10
#define BUCKET_SIZE 1024  // nodes per bucket

static __device__ __forceinline__ unsigned short f2bf(float f) {
    union { float f; unsigned u; } v; v.f = f;
    unsigned r = v.u + 0x7FFF + ((v.u >> 16) & 1);
    return (unsigned short)(r >> 16);
}
static __device__ __forceinline__ float bf2f(unsigned short h) {
    union { unsigned u; float f; } v; v.u = ((unsigned)h) << 16;
    return v.f;
}

// ================= K1: prep — weight swizzles + edge histogram (merged) =================
// blocks [0,128): bsw1; [128,256): bsw2; [256,304): bswL; [304,304+nblk): edge_hist
__global__ __launch_bounds__(256) void prep(const float* __restrict__ Wrel1,
                                            const float* __restrict__ Wroot1,
                                            const float* __restrict__ Wrel2,
                                            const float* __restrict__ Wroot2,
                                            const float* __restrict__ Wlin,
                                            const int* __restrict__ dst,
                                            unsigned short* __restrict__ bsw1,
                                            unsigned short* __restrict__ bsw2,
                                            unsigned short* __restrict__ bswL,
                                            int* __restrict__ hist,
                                            int E, int nblk, int nbuck) {
    __shared__ int h[128];
    int blk = blockIdx.x, t = threadIdx.x;
    if (blk < 256) {
        // build swizzled B = [W_rel | W_root], MFMA B-fragment order
        const float* Wrel  = (blk < 128) ? Wrel1 : Wrel2;
        const float* Wroot = (blk < 128) ? Wroot1 : Wroot2;
        unsigned short* bsw = (blk < 128) ? bsw1 : bsw2;
        int idx = (blk & 127) * 256 + t;  // 32768 total
        int j = idx & 7, L = (idx >> 3) & 63, ct = (idx >> 9) & 15, kt = idx >> 13;
        int k = kt * 32 + ((L >> 4) * 8) + j;
        int c = ct * 16 + (L & 15);
        float v = (c < 128) ? Wrel[k * 128 + c] : Wroot[k * 128 + (c - 128)];
        bsw[idx] = f2bf(v);
    } else if (blk < 304) {
        int idx = (blk - 256) * 256 + t;  // 12288 total
        int tt = idx;
        int j = tt & 7; tt >>= 3;
        int L = tt & 63; tt >>= 6;
        int ct = tt % 3;
        int kt = tt / 3;
        int k = kt * 32 + ((L >> 4) * 8) + j;
        int c = ct * 16 + (L & 15);
        float v = (c < 40) ? Wlin[k * 40 + c] : 0.f;
        bswL[idx] = f2bf(v);
    } else {
        int hb = blk - 304;
        if (t < nbuck) h[t] = 0;
        __syncthreads();
        int e0 = hb * EPB;
#pragma unroll
        for (int it = 0; it < EPB / 256; it++) {
            int e = e0 + it * 256 + t;
            if (e < E) atomicAdd(&h[dst[e] >> BUCKET_BITS], 1);
        }
        __syncthreads();
        if (t < nbuck) hist[t * nblk + hb] = h[t];
    }
}

// ================= K2: all scans in one kernel =================
// block b: recompute all bucket totals from hist, scan -> own base, scan own row in place,
// write bucketBase[b] (and [nbuck]).
__global__ __launch_bounds__(256) void scan_all(int* __restrict__ hist,
                                                int* __restrict__ bucketBase,
                                                int nblk, int nbuck) {
    __shared__ int tot[128];
    __shared__ int s[256];
    int b = blockIdx.x, t = threadIdx.x;
    if (t < 128) tot[t] = 0;
    __syncthreads();
    int len = nbuck * nblk;
    for (int i = t; i < len; i += 256) atomicAdd(&tot[i / nblk], hist[i]);
    __syncthreads();
    // exclusive-ish scan over tot (inclusive in s)
    if (t < 128) s[t] = tot[t];
    __syncthreads();
#pragma unroll
    for (int o = 1; o < 128; o <<= 1) {
        int x = (t < 128 && t >= o) ? s[t - o] : 0;
        __syncthreads();
        if (t < 128) s[t] += x;
        __syncthreads();
    }
    int base_b = s[b] - tot[b];
    int tot_b = tot[b];
    if (t == 0) {
        bucketBase[b] = base_b;
        if (b == nbuck - 1) bucketBase[nbuck] = base_b + tot_b;
    }
    __syncthreads();  // done with s
    // scan own hist row with carry
    int carryv = base_b;
    for (int start = 0; start < nblk; start += 256) {
        int i = start + t;
        int v = (i < nblk) ? hist[b * nblk + i] : 0;
        s[t] = v; __syncthreads();
#pragma unroll
        for (int o = 1; o < 256; o <<= 1) {
            int x = (t >= o) ? s[t - o] : 0;
            __syncthreads();
            s[t] += x; __syncthreads();
        }
        int excl = s[t] - v + carryv;
        if (i < nblk) hist[b * nblk + i] = excl;
        carryv += s[255];
        __syncthreads();
    }
}

// ================= K3: per-chunk LDS counting sort -> bucket-sorted packed records =================
__global__ __launch_bounds__(256) void edge_part(const int* __restrict__ src,
                                                 const int* __restrict__ dst,
                                                 const int* __restrict__ hist,  // block bases
                                                 int* __restrict__ part,
                                                 int E, int nblk, int nbuck) {
    __shared__ int hcnt[128];
    __shared__ int lstart[128];
    __shared__ int cur[128];
    __shared__ int gbase[128];
    __shared__ int ssc[128];
    __shared__ int sdst[EPB];  // 16 KB
    __shared__ int ssrc[EPB];  // 16 KB
    int t = threadIdx.x, blk = blockIdx.x;
    int e0 = blk * EPB;
    int cnt = E - e0; if (cnt > EPB) cnt = EPB;
    if (t < nbuck) { hcnt[t] = 0; gbase[t] = hist[t * nblk + blk]; }
    __syncthreads();
    int myd[EPB / 256], mys[EPB / 256];
#pragma unroll
    for (int it = 0; it < EPB / 256; it++) {
        int i = it * 256 + t;
        if (i < cnt) {
            myd[it] = dst[e0 + i];
            mys[it] = src[e0 + i];
            atomicAdd(&hcnt[myd[it] >> BUCKET_BITS], 1);
        }
    }
    __syncthreads();
    if (t < 128) ssc[t] = (t < nbuck) ? hcnt[t] : 0;
    __syncthreads();
#pragma unroll
    for (int o = 1; o < 128; o <<= 1) {
        int x = 0;
        if (t < 128 && t >= o) x = ssc[t - o];
        __syncthreads();
        if (t < 128) ssc[t] += x;
        __syncthreads();
    }
    if (t < nbuck) { lstart[t] = ssc[t] - hcnt[t]; cur[t] = 0; }
    __syncthreads();
#pragma unroll
    for (int it = 0; it < EPB / 256; it++) {
        int i = it * 256 + t;
        if (i < cnt) {
            int b = myd[it] >> BUCKET_BITS;
            int p = lstart[b] + atomicAdd(&cur[b], 1);
            sdst[p] = myd[it];
            ssrc[p] = mys[it];
        }
    }
    __syncthreads();
    for (int i = t; i < cnt; i += 256) {
        int d = sdst[i], s = ssrc[i];
        int b = d >> BUCKET_BITS;
        part[gbase[b] + (i - lstart[b])] = ((d & (BUCKET_SIZE - 1)) << 17) | s;
    }
}

// ================= K4: per-bucket finalize: deg/off per node + dst-sorted csr_src =================
__global__ __launch_bounds__(256) void csr_finalize(const int* __restrict__ part,
                                                    const int* __restrict__ bucketBase,
                                                    int* __restrict__ off_,
                                                    int* __restrict__ deg_,
                                                    int* __restrict__ csr_src,
                                                    int N) {
    __shared__ int cur[BUCKET_SIZE];   // 4 KB
    __shared__ int h[BUCKET_SIZE];     // 4 KB
    __shared__ int tsum[256];
    int b = blockIdx.x, t = threadIdx.x;
    int lo = bucketBase[b], hi = bucketBase[b + 1];
    int n0 = b * BUCKET_SIZE;
    for (int i = t; i < BUCKET_SIZE; i += 256) h[i] = 0;
    __syncthreads();
    for (int i = lo + t; i < hi; i += 256) atomicAdd(&h[part[i] >> 17], 1);
    __syncthreads();
    int a0 = h[4 * t], a1 = h[4 * t + 1], a2 = h[4 * t + 2], a3 = h[4 * t + 3];
    int ts = a0 + a1 + a2 + a3;
    tsum[t] = ts;
    __syncthreads();
#pragma unroll
    for (int o = 1; o < 256; o <<= 1) {
        int x = (t >= o) ? tsum[t - o] : 0;
        __syncthreads();
        tsum[t] += x;
        __syncthreads();
    }
    int st0 = tsum[t] - ts;
    int st1 = st0 + a0, st2 = st1 + a1, st3 = st2 + a2;
    cur[4 * t] = st0; cur[4 * t + 1] = st1; cur[4 * t + 2] = st2; cur[4 * t + 3] = st3;
    int node = n0 + 4 * t;
    if (node < N)     { off_[node] = lo + st0;     deg_[node] = a0; }
    if (node + 1 < N) { off_[node + 1] = lo + st1; deg_[node + 1] = a1; }
    if (node + 2 < N) { off_[node + 2] = lo + st2; deg_[node + 2] = a2; }
    if (node + 3 < N) { off_[node + 3] = lo + st3; deg_[node + 3] = a3; }
    __syncthreads();
    for (int i = lo + t; i < hi; i += 256) {
        int rec = part[i];
        int p = atomicAdd(&cur[rec >> 17], 1);
        csr_src[lo + p] = rec & 0x1FFFF;
    }
}

// ================= layer GEMM (templated A dtype) =================
// A [N,128] (f32 or bf16) @ Bsw [128,256]bf16 -> xr[N,128]bf16 (cols 0..127),
// accbf[N,128]bf16 = cols 128..255 + bias
template <bool AF32>
__global__ __launch_bounds__(256) void gemm_layer_t(const void* __restrict__ A,
                                                    const unsigned short* __restrict__ Bsw,
                                                    const float* __restrict__ bias,
                                                    unsigned short* __restrict__ xr,
                                                    unsigned short* __restrict__ accbf, int N) {
    int wid = blockIdx.x * 4 + (threadIdx.x >> 6);
    int L = threadIdx.x & 63;
    int r0 = wid * 16;
    if (r0 >= N) return;
    int arow = r0 + (L & 15);
    const bf16x8* Bptr = ((const bf16x8*)Bsw) + L;
    f32x4 acc[16];
#pragma unroll
    for (int i = 0; i < 16; i++) acc[i] = (f32x4){0.f, 0.f, 0.f, 0.f};
#pragma unroll
    for (int kt = 0; kt < 4; kt++) {
        bf16x8 a;
        if (AF32) {
            const float* Arow = ((const float*)A) + (size_t)arow * 128 + ((L >> 4) * 8) + kt * 32;
            float4 a0 = *(const float4*)Arow;
            float4 a1 = *(const float4*)(Arow + 4);
            a[0] = (short)f2bf(a0.x); a[1] = (short)f2bf(a0.y);
            a[2] = (short)f2bf(a0.z); a[3] = (short)f2bf(a0.w);
            a[4] = (short)f2bf(a1.x); a[5] = (short)f2bf(a1.y);
            a[6] = (short)f2bf(a1.z); a[7] = (short)f2bf(a1.w);
        } else {
            a = *((const bf16x8*)(((const unsigned short*)A) + (size_t)arow * 128 + ((L >> 4) * 8) + kt * 32));
        }
#pragma unroll
        for (int ct = 0; ct < 16; ct++) {
            bf16x8 b = Bptr[(kt * 16 + ct) * 64];
            acc[ct] = __builtin_amdgcn_mfma_f32_16x16x32_bf16(a, b, acc[ct], 0, 0, 0);
        }
    }
    int rbase = r0 + (L >> 4) * 4;
    int cl = L & 15;
#pragma unroll
    for (int ct = 0; ct < 16; ct++) {
        int col = ct * 16 + cl;
#pragma unroll
        for (int r = 0; r < 4; r++) {
            int row = rbase + r;
            float v = acc[ct][r];
            if (col < 128)
                xr[(size_t)row * 128 + col] = f2bf(v);
            else
                accbf[(size_t)row * 128 + (col - 128)] = f2bf(v + bias[col - 128]);
        }
    }
}

// ================= gather-aggregate + relu + bf16 convert =================
// one wave per node; 4 edges per dwordx4 load; lane L = (g=L>>4 edge slot, f=L&15 feat-8 group)
__global__ __launch_bounds__(256) void agg_relu_cvt(const unsigned short* __restrict__ xr,
                                                    const unsigned short* __restrict__ accbf,
                                                    const int* __restrict__ off_,
                                                    const int* __restrict__ deg,
                                                    const int* __restrict__ csr_src,
                                                    unsigned short* __restrict__ out, int N) {
    int node = blockIdx.x * 4 + (threadIdx.x >> 6);
    if (node >= N) return;
    int L = threadIdx.x & 63;
    int g = L >> 4;
    int f = L & 15;
    int o = off_[node];
    int d = deg[node];
    float af[8];
#pragma unroll
    for (int i = 0; i < 8; i++) af[i] = 0.f;

    for (int k = 0; k < d; k += 64) {
        int chunk = (d - k < 64) ? (d - k) : 64;
        int id = (L < chunk) ? csr_src[o + k + L] : 0;
        int full = chunk & ~3;
#pragma unroll 4
        for (int j = 0; j < full; j += 4) {
            int s = __shfl(id, j + g, 64);
            bf16x8 p = *(const bf16x8*)(xr + (size_t)s * 128 + f * 8);
#pragma unroll
            for (int i = 0; i < 8; i++) af[i] += bf2f((unsigned short)p[i]);
        }
        if (full < chunk) {
            int sl = full + g;
            int s = __shfl(id, (sl < chunk) ? sl : 0, 64);
            if (sl < chunk) {
                bf16x8 p = *(const bf16x8*)(xr + (size_t)s * 128 + f * 8);
#pragma unroll
                for (int i = 0; i < 8; i++) af[i] += bf2f((unsigned short)p[i]);
            }
        }
    }
#pragma unroll
    for (int i = 0; i < 8; i++) af[i] += __shfl_xor(af[i], 16, 64);
#pragma unroll
    for (int i = 0; i < 8; i++) af[i] += __shfl_xor(af[i], 32, 64);

    if (g == 0) {
        bf16x8 a = *(const bf16x8*)(accbf + (size_t)node * 128 + f * 8);
        uint4 wv;
        unsigned short rlo, rhi;
        rlo = f2bf(fmaxf(bf2f((unsigned short)a[0]) + af[0], 0.f));
        rhi = f2bf(fmaxf(bf2f((unsigned short)a[1]) + af[1], 0.f));
        wv.x = ((unsigned)rhi << 16) | rlo;
        rlo = f2bf(fmaxf(bf2f((unsigned short)a[2]) + af[2], 0.f));
        rhi = f2bf(fmaxf(bf2f((unsigned short)a[3]) + af[3], 0.f));
        wv.y = ((unsigned)rhi << 16) | rlo;
        rlo = f2bf(fmaxf(bf2f((unsigned short)a[4]) + af[4], 0.f));
        rhi = f2bf(fmaxf(bf2f((unsigned short)a[5]) + af[5], 0.f));
        wv.z = ((unsigned)rhi << 16) | rlo;
        rlo = f2bf(fmaxf(bf2f((unsigned short)a[6]) + af[6], 0.f));
        rhi = f2bf(fmaxf(bf2f((unsigned short)a[7]) + af[7], 0.f));
        wv.w = ((unsigned)rhi << 16) | rlo;
        *(uint4*)(out + (size_t)node * 128 + f * 8) = wv;
    }
}

// ================= K9: final GEMM + fused log_softmax =================
__global__ __launch_bounds__(256) void gemm_final_ls(const unsigned short* __restrict__ x1bf,
                                                     const unsigned short* __restrict__ x2bf,
                                                     const unsigned short* __restrict__ Bsw,
                                                     const float* __restrict__ blin,
                                                     float* __restrict__ out, int N) {
    int wid = blockIdx.x * 4 + (threadIdx.x >> 6);
    int L = threadIdx.x & 63;
    int r0 = wid * 16;
    if (r0 >= N) return;
    int arow = r0 + (L & 15);
    f32x4 acc[3];
#pragma unroll
    for (int i = 0; i < 3; i++) acc[i] = (f32x4){0.f, 0.f, 0.f, 0.f};
#pragma unroll
    for (int kt = 0; kt < 8; kt++) {
        const unsigned short* Ab = (kt < 4) ? x1bf : x2bf;
        int kk = (kt & 3) * 32 + ((L >> 4) * 8);
        bf16x8 a = *((const bf16x8*)(Ab + (size_t)arow * 128 + kk));
#pragma unroll
        for (int ct = 0; ct < 3; ct++) {
            bf16x8 b = ((const bf16x8*)Bsw)[(kt * 3 + ct) * 64 + L];
            acc[ct] = __builtin_amdgcn_mfma_f32_16x16x32_bf16(a, b, acc[ct], 0, 0, 0);
        }
    }
    int rbase = r0 + (L >> 4) * 4;
    int cl = L & 15;
    float b0 = blin[cl], b1 = blin[16 + cl];
    float b2 = (cl < 8) ? blin[32 + cl] : 0.f;
#pragma unroll
    for (int r = 0; r < 4; r++) {
        int row = rbase + r;
        float v0 = acc[0][r] + b0;
        float v1 = acc[1][r] + b1;
        float v2 = (cl < 8) ? (acc[2][r] + b2) : -__builtin_inff();
        float m = fmaxf(fmaxf(v0, v1), v2);
#pragma unroll
        for (int off = 8; off >= 1; off >>= 1) m = fmaxf(m, __shfl_xor(m, off, 64));
        float e = __expf(v0 - m) + __expf(v1 - m) + ((cl < 8) ? __expf(v2 - m) : 0.f);
#pragma unroll
        for (int off = 8; off >= 1; off >>= 1) e += __shfl_xor(e, off, 64);
        float ls = m + __logf(e);
        float* op = out + (size_t)row * 40;
        op[cl] = v0 - ls;
        op[16 + cl] = v1 - ls;
        if (cl < 8) op[32 + cl] = v2 - ls;
    }
}

extern "C" void kernel_launch(void* const* d_in, const int* in_sizes, int n_in,
                              void* d_out, int out_size, void* d_ws, size_t ws_size,
                              hipStream_t stream) {
    const float* x      = (const float*)d_in[0];
    const int*   edge   = (const int*)d_in[1];
    const float* Wrel1  = (const float*)d_in[2];
    const float* brel1  = (const float*)d_in[3];
    const float* Wroot1 = (const float*)d_in[4];
    const float* Wrel2  = (const float*)d_in[5];
    const float* brel2  = (const float*)d_in[6];
    const float* Wroot2 = (const float*)d_in[7];
    const float* Wlin   = (const float*)d_in[8];
    const float* blin   = (const float*)d_in[9];

    const int N = in_sizes[0] / 128;
    const int E = in_sizes[1] / 2;
    const int* src = edge;
    const int* dst = edge + E;

    const int nblk  = (E + EPB - 1) / EPB;                    // 391
    const int nbuck = (N + BUCKET_SIZE - 1) / BUCKET_SIZE;    // 98

    char* ws = (char*)d_ws;
    size_t off = 0;
    auto alloc = [&](size_t bytes) -> void* {
        void* p = ws + off;
        off += (bytes + 255) & ~(size_t)255;
        return p;
    };
    unsigned short* x1bf = (unsigned short*)alloc((size_t)N * 128 * 2);
    unsigned short* x2bf = (unsigned short*)alloc((size_t)N * 128 * 2);
    unsigned short* xr   = (unsigned short*)alloc((size_t)N * 128 * 2);
    unsigned short* accbf= (unsigned short*)alloc((size_t)N * 128 * 2);  // shared between layers
    unsigned short* bsw1 = (unsigned short*)alloc(32768 * 2);
    unsigned short* bsw2 = (unsigned short*)alloc(32768 * 2);
    unsigned short* bswL = (unsigned short*)alloc(12288 * 2);
    int* hist       = (int*)alloc((size_t)nbuck * nblk * 4);
    int* bucketBase = (int*)alloc((size_t)(nbuck + 1) * 4);
    int* part       = (int*)alloc((size_t)E * 4);
    int* csr_src    = (int*)alloc((size_t)E * 4);
    int* off_       = (int*)alloc((size_t)N * 4);
    int* deg_       = (int*)alloc((size_t)N * 4);

    const int rowTiles = (N + 15) / 16;
    const int gemmBlocks = (rowTiles + 3) / 4;
    const int nodeBlocks = (N + 3) / 4;

    // K1: weight swizzles + edge histogram
    prep<<<304 + nblk, 256, 0, stream>>>(Wrel1, Wroot1, Wrel2, Wroot2, Wlin, dst,
                                         bsw1, bsw2, bswL, hist, E, nblk, nbuck);
    // K2: all scans
    scan_all<<<nbuck, 256, 0, stream>>>(hist, bucketBase, nblk, nbuck);
    // K3: partition
    edge_part<<<nblk, 256, 0, stream>>>(src, dst, hist, part, E, nblk, nbuck);
    // K4: finalize CSR
    csr_finalize<<<nbuck, 256, 0, stream>>>(part, bucketBase, off_, deg_, csr_src, N);

    // layer 1 (f32 A, in-register cvt)
    gemm_layer_t<true><<<gemmBlocks, 256, 0, stream>>>(x, bsw1, brel1, xr, accbf, N);
    agg_relu_cvt<<<nodeBlocks, 256, 0, stream>>>(xr, accbf, off_, deg_, csr_src, x1bf, N);

    // layer 2 (bf16 A)
    gemm_layer_t<false><<<gemmBlocks, 256, 0, stream>>>(x1bf, bsw2, brel2, xr, accbf, N);
    agg_relu_cvt<<<nodeBlocks, 256, 0, stream>>>(xr, accbf, off_, deg_, csr_src, x2bf, N);

    // classifier + fused log_softmax
    gemm_final_ls<<<gemmBlocks, 256, 0, stream>>>(x1bf, x2bf, bswL, blin, (float*)d_out, N);
}

// Round 7
// 383.111 us; speedup vs baseline: 7.8779x; 1.0649x over previous
//
#include <hip/hip_runtime.h>
#include <hip/hip_bf16.h>

typedef __attribute__((ext_vector_type(8))) short bf16x8;
typedef __attribute__((ext_vector_type(4))) float f32x4;

#define EPB 4096          // edges per partition block
#define BUCKET_BITS 10
#define BUCKET_SIZE 1024  // nodes per bucket

static __device__ __forceinline__ unsigned short f2bf(float f) {
    union { float f; unsigned u; } v; v.f = f;
    unsigned r = v.u + 0x7FFF + ((v.u >> 16) & 1);
    return (unsigned short)(r >> 16);
}
static __device__ __forceinline__ float asf(unsigned u) {
    union { unsigned u; float f; } v; v.u = u;
    return v.f;
}

// ================= K1: prep — weight swizzles + edge histogram (merged) =================
__global__ __launch_bounds__(256) void prep(const float* __restrict__ Wrel1,
                                            const float* __restrict__ Wroot1,
                                            const float* __restrict__ Wrel2,
                                            const float* __restrict__ Wroot2,
                                            const float* __restrict__ Wlin,
                                            const int* __restrict__ dst,
                                            unsigned short* __restrict__ bsw1,
                                            unsigned short* __restrict__ bsw2,
                                            unsigned short* __restrict__ bswL,
                                            int* __restrict__ hist,
                                            int E, int nblk, int nbuck) {
    __shared__ int h[128];
    int blk = blockIdx.x, t = threadIdx.x;
    if (blk < 256) {
        const float* Wrel  = (blk < 128) ? Wrel1 : Wrel2;
        const float* Wroot = (blk < 128) ? Wroot1 : Wroot2;
        unsigned short* bsw = (blk < 128) ? bsw1 : bsw2;
        int idx = (blk & 127) * 256 + t;  // 32768 total
        int j = idx & 7, L = (idx >> 3) & 63, ct = (idx >> 9) & 15, kt = idx >> 13;
        int k = kt * 32 + ((L >> 4) * 8) + j;
        int c = ct * 16 + (L & 15);
        float v = (c < 128) ? Wrel[k * 128 + c] : Wroot[k * 128 + (c - 128)];
        bsw[idx] = f2bf(v);
    } else if (blk < 304) {
        int idx = (blk - 256) * 256 + t;  // 12288 total
        int tt = idx;
        int j = tt & 7; tt >>= 3;
        int L = tt & 63; tt >>= 6;
        int ct = tt % 3;
        int kt = tt / 3;
        int k = kt * 32 + ((L >> 4) * 8) + j;
        int c = ct * 16 + (L & 15);
        float v = (c < 40) ? Wlin[k * 40 + c] : 0.f;
        bswL[idx] = f2bf(v);
    } else {
        int hb = blk - 304;
        if (t < nbuck) h[t] = 0;
        __syncthreads();
        int e0 = hb * EPB;
#pragma unroll
        for (int it = 0; it < EPB / 256; it++) {
            int e = e0 + it * 256 + t;
            if (e < E) atomicAdd(&h[dst[e] >> BUCKET_BITS], 1);
        }
        __syncthreads();
        if (t < nbuck) hist[t * nblk + hb] = h[t];
    }
}

// ================= K2: all scans in one kernel =================
__global__ __launch_bounds__(256) void scan_all(int* __restrict__ hist,
                                                int* __restrict__ bucketBase,
                                                int nblk, int nbuck) {
    __shared__ int tot[128];
    __shared__ int s[256];
    int b = blockIdx.x, t = threadIdx.x;
    if (t < 128) tot[t] = 0;
    __syncthreads();
    int len = nbuck * nblk;
    for (int i = t; i < len; i += 256) atomicAdd(&tot[i / nblk], hist[i]);
    __syncthreads();
    if (t < 128) s[t] = tot[t];
    __syncthreads();
#pragma unroll
    for (int o = 1; o < 128; o <<= 1) {
        int x = (t < 128 && t >= o) ? s[t - o] : 0;
        __syncthreads();
        if (t < 128) s[t] += x;
        __syncthreads();
    }
    int base_b = s[b] - tot[b];
    int tot_b = tot[b];
    if (t == 0) {
        bucketBase[b] = base_b;
        if (b == nbuck - 1) bucketBase[nbuck] = base_b + tot_b;
    }
    __syncthreads();
    int carryv = base_b;
    for (int start = 0; start < nblk; start += 256) {
        int i = start + t;
        int v = (i < nblk) ? hist[b * nblk + i] : 0;
        s[t] = v; __syncthreads();
#pragma unroll
        for (int o = 1; o < 256; o <<= 1) {
            int x = (t >= o) ? s[t - o] : 0;
            __syncthreads();
            s[t] += x; __syncthreads();
        }
        int excl = s[t] - v + carryv;
        if (i < nblk) hist[b * nblk + i] = excl;
        carryv += s[255];
        __syncthreads();
    }
}

// ================= K3: per-chunk LDS counting sort -> bucket-sorted packed records =================
__global__ __launch_bounds__(256) void edge_part(const int* __restrict__ src,
                                                 const int* __restrict__ dst,
                                                 const int* __restrict__ hist,  // block bases
                                                 int* __restrict__ part,
                                                 int E, int nblk, int nbuck) {
    __shared__ int hcnt[128];
    __shared__ int lstart[128];
    __shared__ int cur[128];
    __shared__ int gbase[128];
    __shared__ int ssc[128];
    __shared__ int sdst[EPB];  // 16 KB
    __shared__ int ssrc[EPB];  // 16 KB
    int t = threadIdx.x, blk = blockIdx.x;
    int e0 = blk * EPB;
    int cnt = E - e0; if (cnt > EPB) cnt = EPB;
    if (t < nbuck) { hcnt[t] = 0; gbase[t] = hist[t * nblk + blk]; }
    __syncthreads();
    int myd[EPB / 256], mys[EPB / 256];
#pragma unroll
    for (int it = 0; it < EPB / 256; it++) {
        int i = it * 256 + t;
        if (i < cnt) {
            myd[it] = dst[e0 + i];
            mys[it] = src[e0 + i];
            atomicAdd(&hcnt[myd[it] >> BUCKET_BITS], 1);
        }
    }
    __syncthreads();
    if (t < 128) ssc[t] = (t < nbuck) ? hcnt[t] : 0;
    __syncthreads();
#pragma unroll
    for (int o = 1; o < 128; o <<= 1) {
        int x = 0;
        if (t < 128 && t >= o) x = ssc[t - o];
        __syncthreads();
        if (t < 128) ssc[t] += x;
        __syncthreads();
    }
    if (t < nbuck) { lstart[t] = ssc[t] - hcnt[t]; cur[t] = 0; }
    __syncthreads();
#pragma unroll
    for (int it = 0; it < EPB / 256; it++) {
        int i = it * 256 + t;
        if (i < cnt) {
            int b = myd[it] >> BUCKET_BITS;
            int p = lstart[b] + atomicAdd(&cur[b], 1);
            sdst[p] = myd[it];
            ssrc[p] = mys[it];
        }
    }
    __syncthreads();
    for (int i = t; i < cnt; i += 256) {
        int d = sdst[i], s = ssrc[i];
        int b = d >> BUCKET_BITS;
        part[gbase[b] + (i - lstart[b])] = ((d & (BUCKET_SIZE - 1)) << 17) | s;
    }
}

// ================= K4: csr_finalize (blocks 0..nbuck-1) + layer-1 GEMM (rest), merged =================
// csr blocks are latency-bound on 98 blocks (38% of CUs); gemm1 is independent and fills the rest.
__global__ __launch_bounds__(256) void csrfin_gemm1(const int* __restrict__ part,
                                                    const int* __restrict__ bucketBase,
                                                    int* __restrict__ off_,
                                                    int* __restrict__ deg_,
                                                    int* __restrict__ csr_src,
                                                    const float* __restrict__ x,
                                                    const unsigned short* __restrict__ Bsw,
                                                    const float* __restrict__ bias,
                                                    unsigned short* __restrict__ xr,
                                                    unsigned short* __restrict__ accbf,
                                                    int N, int nbuck) {
    __shared__ int cur[BUCKET_SIZE];   // 4 KB
    __shared__ int h[BUCKET_SIZE];     // 4 KB
    __shared__ int tsum[256];
    int t = threadIdx.x;
    if (blockIdx.x < (unsigned)nbuck) {
        int b = blockIdx.x;
        int lo = bucketBase[b], hi = bucketBase[b + 1];
        int n0 = b * BUCKET_SIZE;
        for (int i = t; i < BUCKET_SIZE; i += 256) h[i] = 0;
        __syncthreads();
        for (int i = lo + t; i < hi; i += 256) atomicAdd(&h[part[i] >> 17], 1);
        __syncthreads();
        int a0 = h[4 * t], a1 = h[4 * t + 1], a2 = h[4 * t + 2], a3 = h[4 * t + 3];
        int ts = a0 + a1 + a2 + a3;
        tsum[t] = ts;
        __syncthreads();
#pragma unroll
        for (int o = 1; o < 256; o <<= 1) {
            int xx = (t >= o) ? tsum[t - o] : 0;
            __syncthreads();
            tsum[t] += xx;
            __syncthreads();
        }
        int st0 = tsum[t] - ts;
        int st1 = st0 + a0, st2 = st1 + a1, st3 = st2 + a2;
        cur[4 * t] = st0; cur[4 * t + 1] = st1; cur[4 * t + 2] = st2; cur[4 * t + 3] = st3;
        int node = n0 + 4 * t;
        if (node < N)     { off_[node] = lo + st0;     deg_[node] = a0; }
        if (node + 1 < N) { off_[node + 1] = lo + st1; deg_[node + 1] = a1; }
        if (node + 2 < N) { off_[node + 2] = lo + st2; deg_[node + 2] = a2; }
        if (node + 3 < N) { off_[node + 3] = lo + st3; deg_[node + 3] = a3; }
        __syncthreads();
        for (int i = lo + t; i < hi; i += 256) {
            int rec = part[i];
            int p = atomicAdd(&cur[rec >> 17], 1);
            csr_src[lo + p] = rec & 0x1FFFF;
        }
    } else {
        int wid = (blockIdx.x - nbuck) * 4 + (t >> 6);
        int L = t & 63;
        int r0 = wid * 16;
        if (r0 >= N) return;
        int arow = r0 + (L & 15);
        const bf16x8* Bptr = ((const bf16x8*)Bsw) + L;
        f32x4 acc[16];
#pragma unroll
        for (int i = 0; i < 16; i++) acc[i] = (f32x4){0.f, 0.f, 0.f, 0.f};
#pragma unroll
        for (int kt = 0; kt < 4; kt++) {
            const float* Arow = x + (size_t)arow * 128 + ((L >> 4) * 8) + kt * 32;
            float4 a0 = *(const float4*)Arow;
            float4 a1 = *(const float4*)(Arow + 4);
            bf16x8 a;
            a[0] = (short)f2bf(a0.x); a[1] = (short)f2bf(a0.y);
            a[2] = (short)f2bf(a0.z); a[3] = (short)f2bf(a0.w);
            a[4] = (short)f2bf(a1.x); a[5] = (short)f2bf(a1.y);
            a[6] = (short)f2bf(a1.z); a[7] = (short)f2bf(a1.w);
#pragma unroll
            for (int ct = 0; ct < 16; ct++) {
                bf16x8 b = Bptr[(kt * 16 + ct) * 64];
                acc[ct] = __builtin_amdgcn_mfma_f32_16x16x32_bf16(a, b, acc[ct], 0, 0, 0);
            }
        }
        int rbase = r0 + (L >> 4) * 4;
        int cl = L & 15;
#pragma unroll
        for (int ct = 0; ct < 16; ct++) {
            int col = ct * 16 + cl;
#pragma unroll
            for (int r = 0; r < 4; r++) {
                int row = rbase + r;
                float v = acc[ct][r];
                if (col < 128)
                    xr[(size_t)row * 128 + col] = f2bf(v);
                else
                    accbf[(size_t)row * 128 + (col - 128)] = f2bf(v + bias[col - 128]);
            }
        }
    }
}

// ================= layer-2 GEMM (bf16 A) =================
__global__ __launch_bounds__(256) void gemm_layer2(const unsigned short* __restrict__ Abf,
                                                   const unsigned short* __restrict__ Bsw,
                                                   const float* __restrict__ bias,
                                                   unsigned short* __restrict__ xr,
                                                   unsigned short* __restrict__ accbf, int N) {
    int wid = blockIdx.x * 4 + (threadIdx.x >> 6);
    int L = threadIdx.x & 63;
    int r0 = wid * 16;
    if (r0 >= N) return;
    int arow = r0 + (L & 15);
    const bf16x8* Bptr = ((const bf16x8*)Bsw) + L;
    f32x4 acc[16];
#pragma unroll
    for (int i = 0; i < 16; i++) acc[i] = (f32x4){0.f, 0.f, 0.f, 0.f};
#pragma unroll
    for (int kt = 0; kt < 4; kt++) {
        bf16x8 a = *((const bf16x8*)(Abf + (size_t)arow * 128 + ((L >> 4) * 8) + kt * 32));
#pragma unroll
        for (int ct = 0; ct < 16; ct++) {
            bf16x8 b = Bptr[(kt * 16 + ct) * 64];
            acc[ct] = __builtin_amdgcn_mfma_f32_16x16x32_bf16(a, b, acc[ct], 0, 0, 0);
        }
    }
    int rbase = r0 + (L >> 4) * 4;
    int cl = L & 15;
#pragma unroll
    for (int ct = 0; ct < 16; ct++) {
        int col = ct * 16 + cl;
#pragma unroll
        for (int r = 0; r < 4; r++) {
            int row = rbase + r;
            float v = acc[ct][r];
            if (col < 128)
                xr[(size_t)row * 128 + col] = f2bf(v);
            else
                accbf[(size_t)row * 128 + (col - 128)] = f2bf(v + bias[col - 128]);
        }
    }
}

// ================= gather-aggregate + relu + bf16 convert =================
// one wave per node; 4 edges per dwordx4 load; packed bf16->f32 via shift/mask (bit-exact)
__global__ __launch_bounds__(256) void agg_relu_cvt(const unsigned short* __restrict__ xr,
                                                    const unsigned short* __restrict__ accbf,
                                                    const int* __restrict__ off_,
                                                    const int* __restrict__ deg,
                                                    const int* __restrict__ csr_src,
                                                    unsigned short* __restrict__ out, int N) {
    int node = blockIdx.x * 4 + (threadIdx.x >> 6);
    if (node >= N) return;
    int L = threadIdx.x & 63;
    int g = L >> 4;
    int f = L & 15;
    int o = off_[node];
    int d = deg[node];
    // hoist acc-row load (only needed by g==0 lanes at the end)
    uint4 arow = (uint4){0, 0, 0, 0};
    if (g == 0) arow = *(const uint4*)(accbf + (size_t)node * 128 + f * 8);

    float lo0 = 0.f, lo1 = 0.f, lo2 = 0.f, lo3 = 0.f;
    float hi0 = 0.f, hi1 = 0.f, hi2 = 0.f, hi3 = 0.f;

    for (int k = 0; k < d; k += 64) {
        int chunk = (d - k < 64) ? (d - k) : 64;
        int id = (L < chunk) ? csr_src[o + k + L] : 0;
        int full = chunk & ~3;
#pragma unroll 4
        for (int j = 0; j < full; j += 4) {
            int s = __shfl(id, j + g, 64);
            uint4 p = *(const uint4*)(xr + (size_t)s * 128 + f * 8);
            lo0 += asf(p.x << 16); hi0 += asf(p.x & 0xFFFF0000u);
            lo1 += asf(p.y << 16); hi1 += asf(p.y & 0xFFFF0000u);
            lo2 += asf(p.z << 16); hi2 += asf(p.z & 0xFFFF0000u);
            lo3 += asf(p.w << 16); hi3 += asf(p.w & 0xFFFF0000u);
        }
        if (full < chunk) {
            int sl = full + g;
            int s = __shfl(id, (sl < chunk) ? sl : 0, 64);
            if (sl < chunk) {
                uint4 p = *(const uint4*)(xr + (size_t)s * 128 + f * 8);
                lo0 += asf(p.x << 16); hi0 += asf(p.x & 0xFFFF0000u);
                lo1 += asf(p.y << 16); hi1 += asf(p.y & 0xFFFF0000u);
                lo2 += asf(p.z << 16); hi2 += asf(p.z & 0xFFFF0000u);
                lo3 += asf(p.w << 16); hi3 += asf(p.w & 0xFFFF0000u);
            }
        }
    }
    lo0 += __shfl_xor(lo0, 16, 64); hi0 += __shfl_xor(hi0, 16, 64);
    lo1 += __shfl_xor(lo1, 16, 64); hi1 += __shfl_xor(hi1, 16, 64);
    lo2 += __shfl_xor(lo2, 16, 64); hi2 += __shfl_xor(hi2, 16, 64);
    lo3 += __shfl_xor(lo3, 16, 64); hi3 += __shfl_xor(hi3, 16, 64);
    lo0 += __shfl_xor(lo0, 32, 64); hi0 += __shfl_xor(hi0, 32, 64);
    lo1 += __shfl_xor(lo1, 32, 64); hi1 += __shfl_xor(hi1, 32, 64);
    lo2 += __shfl_xor(lo2, 32, 64); hi2 += __shfl_xor(hi2, 32, 64);
    lo3 += __shfl_xor(lo3, 32, 64); hi3 += __shfl_xor(hi3, 32, 64);

    if (g == 0) {
        uint4 wv;
        wv.x = ((unsigned)f2bf(fmaxf(asf(arow.x & 0xFFFF0000u) + hi0, 0.f)) << 16)
             | f2bf(fmaxf(asf(arow.x << 16) + lo0, 0.f));
        wv.y = ((unsigned)f2bf(fmaxf(asf(arow.y & 0xFFFF0000u) + hi1, 0.f)) << 16)
             | f2bf(fmaxf(asf(arow.y << 16) + lo1, 0.f));
        wv.z = ((unsigned)f2bf(fmaxf(asf(arow.z & 0xFFFF0000u) + hi2, 0.f)) << 16)
             | f2bf(fmaxf(asf(arow.z << 16) + lo2, 0.f));
        wv.w = ((unsigned)f2bf(fmaxf(asf(arow.w & 0xFFFF0000u) + hi3, 0.f)) << 16)
             | f2bf(fmaxf(asf(arow.w << 16) + lo3, 0.f));
        *(uint4*)(out + (size_t)node * 128 + f * 8) = wv;
    }
}

// ================= final GEMM + fused log_softmax =================
__global__ __launch_bounds__(256) void gemm_final_ls(const unsigned short* __restrict__ x1bf,
                                                     const unsigned short* __restrict__ x2bf,
                                                     const unsigned short* __restrict__ Bsw,
                                                     const float* __restrict__ blin,
                                                     float* __restrict__ out, int N) {
    int wid = blockIdx.x * 4 + (threadIdx.x >> 6);
    int L = threadIdx.x & 63;
    int r0 = wid * 16;
    if (r0 >= N) return;
    int arow = r0 + (L & 15);
    f32x4 acc[3];
#pragma unroll
    for (int i = 0; i < 3; i++) acc[i] = (f32x4){0.f, 0.f, 0.f, 0.f};
#pragma unroll
    for (int kt = 0; kt < 8; kt++) {
        const unsigned short* Ab = (kt < 4) ? x1bf : x2bf;
        int kk = (kt & 3) * 32 + ((L >> 4) * 8);
        bf16x8 a = *((const bf16x8*)(Ab + (size_t)arow * 128 + kk));
#pragma unroll
        for (int ct = 0; ct < 3; ct++) {
            bf16x8 b = ((const bf16x8*)Bsw)[(kt * 3 + ct) * 64 + L];
            acc[ct] = __builtin_amdgcn_mfma_f32_16x16x32_bf16(a, b, acc[ct], 0, 0, 0);
        }
    }
    int rbase = r0 + (L >> 4) * 4;
    int cl = L & 15;
    float b0 = blin[cl], b1 = blin[16 + cl];
    float b2 = (cl < 8) ? blin[32 + cl] : 0.f;
#pragma unroll
    for (int r = 0; r < 4; r++) {
        int row = rbase + r;
        float v0 = acc[0][r] + b0;
        float v1 = acc[1][r] + b1;
        float v2 = (cl < 8) ? (acc[2][r] + b2) : -__builtin_inff();
        float m = fmaxf(fmaxf(v0, v1), v2);
#pragma unroll
        for (int off = 8; off >= 1; off >>= 1) m = fmaxf(m, __shfl_xor(m, off, 64));
        float e = __expf(v0 - m) + __expf(v1 - m) + ((cl < 8) ? __expf(v2 - m) : 0.f);
#pragma unroll
        for (int off = 8; off >= 1; off >>= 1) e += __shfl_xor(e, off, 64);
        float ls = m + __logf(e);
        float* op = out + (size_t)row * 40;
        op[cl] = v0 - ls;
        op[16 + cl] = v1 - ls;
        if (cl < 8) op[32 + cl] = v2 - ls;
    }
}

extern "C" void kernel_launch(void* const* d_in, const int* in_sizes, int n_in,
                              void* d_out, int out_size, void* d_ws, size_t ws_size,
                              hipStream_t stream) {
    const float* x      = (const float*)d_in[0];
    const int*   edge   = (const int*)d_in[1];
    const float* Wrel1  = (const float*)d_in[2];
    const float* brel1  = (const float*)d_in[3];
    const float* Wroot1 = (const float*)d_in[4];
    const float* Wrel2  = (const float*)d_in[5];
    const float* brel2  = (const float*)d_in[6];
    const float* Wroot2 = (const float*)d_in[7];
    const float* Wlin   = (const float*)d_in[8];
    const float* blin   = (const float*)d_in[9];

    const int N = in_sizes[0] / 128;
    const int E = in_sizes[1] / 2;
    const int* src = edge;
    const int* dst = edge + E;

    const int nblk  = (E + EPB - 1) / EPB;                    // 391
    const int nbuck = (N + BUCKET_SIZE - 1) / BUCKET_SIZE;    // 98

    char* ws = (char*)d_ws;
    size_t off = 0;
    auto alloc = [&](size_t bytes) -> void* {
        void* p = ws + off;
        off += (bytes + 255) & ~(size_t)255;
        return p;
    };
    unsigned short* x1bf = (unsigned short*)alloc((size_t)N * 128 * 2);
    unsigned short* x2bf = (unsigned short*)alloc((size_t)N * 128 * 2);
    unsigned short* xr   = (unsigned short*)alloc((size_t)N * 128 * 2);
    unsigned short* accbf= (unsigned short*)alloc((size_t)N * 128 * 2);
    unsigned short* bsw1 = (unsigned short*)alloc(32768 * 2);
    unsigned short* bsw2 = (unsigned short*)alloc(32768 * 2);
    unsigned short* bswL = (unsigned short*)alloc(12288 * 2);
    int* hist       = (int*)alloc((size_t)nbuck * nblk * 4);
    int* bucketBase = (int*)alloc((size_t)(nbuck + 1) * 4);
    int* part       = (int*)alloc((size_t)E * 4);
    int* csr_src    = (int*)alloc((size_t)E * 4);
    int* off_       = (int*)alloc((size_t)N * 4);
    int* deg_       = (int*)alloc((size_t)N * 4);

    const int rowTiles = (N + 15) / 16;
    const int gemmBlocks = (rowTiles + 3) / 4;
    const int nodeBlocks = (N + 3) / 4;

    // K1: weight swizzles + edge histogram
    prep<<<304 + nblk, 256, 0, stream>>>(Wrel1, Wroot1, Wrel2, Wroot2, Wlin, dst,
                                         bsw1, bsw2, bswL, hist, E, nblk, nbuck);
    // K2: all scans
    scan_all<<<nbuck, 256, 0, stream>>>(hist, bucketBase, nblk, nbuck);
    // K3: partition
    edge_part<<<nblk, 256, 0, stream>>>(src, dst, hist, part, E, nblk, nbuck);
    // K4: CSR finalize (98 blocks) + layer-1 GEMM (independent) in one launch
    csrfin_gemm1<<<nbuck + gemmBlocks, 256, 0, stream>>>(part, bucketBase, off_, deg_, csr_src,
                                                         x, bsw1, brel1, xr, accbf, N, nbuck);
    // K5: layer-1 aggregation
    agg_relu_cvt<<<nodeBlocks, 256, 0, stream>>>(xr, accbf, off_, deg_, csr_src, x1bf, N);
    // K6: layer-2 GEMM
    gemm_layer2<<<gemmBlocks, 256, 0, stream>>>(x1bf, bsw2, brel2, xr, accbf, N);
    // K7: layer-2 aggregation
    agg_relu_cvt<<<nodeBlocks, 256, 0, stream>>>(xr, accbf, off_, deg_, csr_src, x2bf, N);
    // K8: classifier + fused log_softmax
    gemm_final_ls<<<gemmBlocks, 256, 0, stream>>>(x1bf, x2bf, bswL, blin, (float*)d_out, N);
}

// Round 8
// 346.137 us; speedup vs baseline: 8.7194x; 1.1068x over previous
//
#include <hip/hip_runtime.h>
#include <hip/hip_bf16.h>

typedef __attribute__((ext_vector_type(8))) short bf16x8;
typedef __attribute__((ext_vector_type(4))) float f32x4;

#define EPB 4096         // edges per partition block
#define BUCKET_BITS 8
#define BUCKET_SIZE 256  // nodes per bucket
#define MAXBUCK 512

static __device__ __forceinline__ unsigned short f2bf(float f) {
    union { float f; unsigned u; } v; v.f = f;
    unsigned r = v.u + 0x7FFF + ((v.u >> 16) & 1);
    return (unsigned short)(r >> 16);
}
static __device__ __forceinline__ float asf(unsigned u) {
    union { unsigned u; float f; } v; v.u = u;
    return v.f;
}

// ================= K1: prep — weight swizzles + edge histogram (merged) =================
__global__ __launch_bounds__(256) void prep(const float* __restrict__ Wrel1,
                                            const float* __restrict__ Wroot1,
                                            const float* __restrict__ Wrel2,
                                            const float* __restrict__ Wroot2,
                                            const float* __restrict__ Wlin,
                                            const int* __restrict__ dst,
                                            unsigned short* __restrict__ bsw1,
                                            unsigned short* __restrict__ bsw2,
                                            unsigned short* __restrict__ bswL,
                                            int* __restrict__ hist,
                                            int E, int nblk, int nbuck) {
    __shared__ int h[MAXBUCK];
    int blk = blockIdx.x, t = threadIdx.x;
    if (blk < 256) {
        const float* Wrel  = (blk < 128) ? Wrel1 : Wrel2;
        const float* Wroot = (blk < 128) ? Wroot1 : Wroot2;
        unsigned short* bsw = (blk < 128) ? bsw1 : bsw2;
        int idx = (blk & 127) * 256 + t;  // 32768 total
        int j = idx & 7, L = (idx >> 3) & 63, ct = (idx >> 9) & 15, kt = idx >> 13;
        int k = kt * 32 + ((L >> 4) * 8) + j;
        int c = ct * 16 + (L & 15);
        float v = (c < 128) ? Wrel[k * 128 + c] : Wroot[k * 128 + (c - 128)];
        bsw[idx] = f2bf(v);
    } else if (blk < 304) {
        int idx = (blk - 256) * 256 + t;  // 12288 total
        int tt = idx;
        int j = tt & 7; tt >>= 3;
        int L = tt & 63; tt >>= 6;
        int ct = tt % 3;
        int kt = tt / 3;
        int k = kt * 32 + ((L >> 4) * 8) + j;
        int c = ct * 16 + (L & 15);
        float v = (c < 40) ? Wlin[k * 40 + c] : 0.f;
        bswL[idx] = f2bf(v);
    } else {
        int hb = blk - 304;
        for (int i = t; i < MAXBUCK; i += 256) h[i] = 0;
        __syncthreads();
        int e0 = hb * EPB;
#pragma unroll
        for (int it = 0; it < EPB / 256; it++) {
            int e = e0 + it * 256 + t;
            if (e < E) atomicAdd(&h[dst[e] >> BUCKET_BITS], 1);
        }
        __syncthreads();
        for (int i = t; i < nbuck; i += 256) hist[i * nblk + hb] = h[i];
    }
}

// ================= K2a: bucket totals =================
__global__ __launch_bounds__(256) void bucket_total(const int* __restrict__ hist,
                                                    int* __restrict__ total, int nblk) {
    __shared__ int s[256];
    int b = blockIdx.x, t = threadIdx.x;
    int v = 0;
    for (int i = t; i < nblk; i += 256) v += hist[b * nblk + i];
    s[t] = v; __syncthreads();
#pragma unroll
    for (int o = 128; o >= 1; o >>= 1) {
        if (t < o) s[t] += s[t + o];
        __syncthreads();
    }
    if (t == 0) total[b] = s[0];
}

// ================= K2b: exclusive scan of bucket totals (pair-scan, nbuck <= 512) =================
__global__ __launch_bounds__(256) void bucket_scan(const int* __restrict__ total,
                                                   int* __restrict__ base, int nbuck) {
    __shared__ int s[256];
    int t = threadIdx.x;
    int e0 = (2 * t < nbuck) ? total[2 * t] : 0;
    int e1 = (2 * t + 1 < nbuck) ? total[2 * t + 1] : 0;
    int ps = e0 + e1;
    s[t] = ps; __syncthreads();
#pragma unroll
    for (int o = 1; o < 256; o <<= 1) {
        int x = (t >= o) ? s[t - o] : 0;
        __syncthreads();
        s[t] += x; __syncthreads();
    }
    int pbase = s[t] - ps;
    if (2 * t <= nbuck) base[2 * t] = pbase;
    if (2 * t + 1 <= nbuck) base[2 * t + 1] = pbase + e0;
}

// ================= K2c: per-bucket scan over blocks -> global slot bases (in place) =================
__global__ __launch_bounds__(256) void block_scan(int* __restrict__ hist,
                                                  const int* __restrict__ base, int nblk) {
    __shared__ int s[256];
    int b = blockIdx.x, t = threadIdx.x;
    int carryv = base[b];
    for (int start = 0; start < nblk; start += 256) {
        int i = start + t;
        int v = (i < nblk) ? hist[b * nblk + i] : 0;
        s[t] = v; __syncthreads();
#pragma unroll
        for (int o = 1; o < 256; o <<= 1) {
            int x = (t >= o) ? s[t - o] : 0;
            __syncthreads();
            s[t] += x; __syncthreads();
        }
        int excl = s[t] - v + carryv;
        if (i < nblk) hist[b * nblk + i] = excl;
        carryv += s[255];
        __syncthreads();
    }
}

// ================= K3: per-chunk LDS counting sort -> bucket-sorted packed records =================
__global__ __launch_bounds__(256) void edge_part(const int* __restrict__ src,
                                                 const int* __restrict__ dst,
                                                 const int* __restrict__ hist,  // block bases
                                                 int* __restrict__ part,
                                                 int E, int nblk, int nbuck) {
    __shared__ int hcnt[MAXBUCK];
    __shared__ int lstart[MAXBUCK];
    __shared__ int cur[MAXBUCK];
    __shared__ int gbase[MAXBUCK];
    __shared__ int s2[256];
    __shared__ int sdst[EPB];  // 16 KB
    __shared__ int ssrc[EPB];  // 16 KB
    int t = threadIdx.x, blk = blockIdx.x;
    int e0 = blk * EPB;
    int cnt = E - e0; if (cnt > EPB) cnt = EPB;
    for (int i = t; i < MAXBUCK; i += 256) hcnt[i] = 0;
    for (int i = t; i < nbuck; i += 256) gbase[i] = hist[i * nblk + blk];
    __syncthreads();
    int myd[EPB / 256], mys[EPB / 256];
#pragma unroll
    for (int it = 0; it < EPB / 256; it++) {
        int i = it * 256 + t;
        if (i < cnt) {
            myd[it] = dst[e0 + i];
            mys[it] = src[e0 + i];
            atomicAdd(&hcnt[myd[it] >> BUCKET_BITS], 1);
        }
    }
    __syncthreads();
    // pair-scan over 512 bins with 256 threads
    int p0 = hcnt[2 * t], p1 = hcnt[2 * t + 1];
    int ps = p0 + p1;
    s2[t] = ps; __syncthreads();
#pragma unroll
    for (int o = 1; o < 256; o <<= 1) {
        int x = (t >= o) ? s2[t - o] : 0;
        __syncthreads();
        s2[t] += x; __syncthreads();
    }
    int pbase = s2[t] - ps;
    lstart[2 * t] = pbase; lstart[2 * t + 1] = pbase + p0;
    cur[2 * t] = 0; cur[2 * t + 1] = 0;
    __syncthreads();
#pragma unroll
    for (int it = 0; it < EPB / 256; it++) {
        int i = it * 256 + t;
        if (i < cnt) {
            int b = myd[it] >> BUCKET_BITS;
            int p = lstart[b] + atomicAdd(&cur[b], 1);
            sdst[p] = myd[it];
            ssrc[p] = mys[it];
        }
    }
    __syncthreads();
    for (int i = t; i < cnt; i += 256) {
        int d = sdst[i], s = ssrc[i];
        int b = d >> BUCKET_BITS;
        part[gbase[b] + (i - lstart[b])] = ((d & (BUCKET_SIZE - 1)) << 17) | s;
    }
}

// ================= K4: csr_finalize (blocks 0..nbuck-1) + layer-1 GEMM (rest), merged =================
__global__ __launch_bounds__(256) void csrfin_gemm1(const int* __restrict__ part,
                                                    const int* __restrict__ bucketBase,
                                                    int* __restrict__ off_,
                                                    int* __restrict__ deg_,
                                                    int* __restrict__ csr_src,
                                                    const float* __restrict__ x,
                                                    const unsigned short* __restrict__ Bsw,
                                                    const float* __restrict__ bias,
                                                    unsigned short* __restrict__ xr,
                                                    unsigned short* __restrict__ accbf,
                                                    int N, int nbuck) {
    __shared__ int cur[BUCKET_SIZE];
    __shared__ int h[BUCKET_SIZE];
    __shared__ int tsum[256];
    int t = threadIdx.x;
    if (blockIdx.x < (unsigned)nbuck) {
        int b = blockIdx.x;
        int lo = bucketBase[b], hi = bucketBase[b + 1];
        int n0 = b * BUCKET_SIZE;
        h[t] = 0;
        __syncthreads();
        for (int i = lo + t; i < hi; i += 256) atomicAdd(&h[part[i] >> 17], 1);
        __syncthreads();
        int hv = h[t];
        tsum[t] = hv;
        __syncthreads();
#pragma unroll
        for (int o = 1; o < 256; o <<= 1) {
            int xx = (t >= o) ? tsum[t - o] : 0;
            __syncthreads();
            tsum[t] += xx;
            __syncthreads();
        }
        int st = tsum[t] - hv;
        cur[t] = st;
        int node = n0 + t;
        if (node < N) { off_[node] = lo + st; deg_[node] = hv; }
        __syncthreads();
        for (int i = lo + t; i < hi; i += 256) {
            int rec = part[i];
            int p = atomicAdd(&cur[rec >> 17], 1);
            csr_src[lo + p] = rec & 0x1FFFF;
        }
    } else {
        int wid = (blockIdx.x - nbuck) * 4 + (t >> 6);
        int L = t & 63;
        int r0 = wid * 16;
        if (r0 >= N) return;
        int arow = r0 + (L & 15);
        const bf16x8* Bptr = ((const bf16x8*)Bsw) + L;
        f32x4 acc[16];
#pragma unroll
        for (int i = 0; i < 16; i++) acc[i] = (f32x4){0.f, 0.f, 0.f, 0.f};
#pragma unroll
        for (int kt = 0; kt < 4; kt++) {
            const float* Arow = x + (size_t)arow * 128 + ((L >> 4) * 8) + kt * 32;
            float4 a0 = *(const float4*)Arow;
            float4 a1 = *(const float4*)(Arow + 4);
            bf16x8 a;
            a[0] = (short)f2bf(a0.x); a[1] = (short)f2bf(a0.y);
            a[2] = (short)f2bf(a0.z); a[3] = (short)f2bf(a0.w);
            a[4] = (short)f2bf(a1.x); a[5] = (short)f2bf(a1.y);
            a[6] = (short)f2bf(a1.z); a[7] = (short)f2bf(a1.w);
#pragma unroll
            for (int ct = 0; ct < 16; ct++) {
                bf16x8 b = Bptr[(kt * 16 + ct) * 64];
                acc[ct] = __builtin_amdgcn_mfma_f32_16x16x32_bf16(a, b, acc[ct], 0, 0, 0);
            }
        }
        int rbase = r0 + (L >> 4) * 4;
        int cl = L & 15;
#pragma unroll
        for (int ct = 0; ct < 16; ct++) {
            int col = ct * 16 + cl;
#pragma unroll
            for (int r = 0; r < 4; r++) {
                int row = rbase + r;
                float v = acc[ct][r];
                if (col < 128)
                    xr[(size_t)row * 128 + col] = f2bf(v);
                else
                    accbf[(size_t)row * 128 + (col - 128)] = f2bf(v + bias[col - 128]);
            }
        }
    }
}

// ================= layer-2 GEMM (bf16 A) =================
__global__ __launch_bounds__(256) void gemm_layer2(const unsigned short* __restrict__ Abf,
                                                   const unsigned short* __restrict__ Bsw,
                                                   const float* __restrict__ bias,
                                                   unsigned short* __restrict__ xr,
                                                   unsigned short* __restrict__ accbf, int N) {
    int wid = blockIdx.x * 4 + (threadIdx.x >> 6);
    int L = threadIdx.x & 63;
    int r0 = wid * 16;
    if (r0 >= N) return;
    int arow = r0 + (L & 15);
    const bf16x8* Bptr = ((const bf16x8*)Bsw) + L;
    f32x4 acc[16];
#pragma unroll
    for (int i = 0; i < 16; i++) acc[i] = (f32x4){0.f, 0.f, 0.f, 0.f};
#pragma unroll
    for (int kt = 0; kt < 4; kt++) {
        bf16x8 a = *((const bf16x8*)(Abf + (size_t)arow * 128 + ((L >> 4) * 8) + kt * 32));
#pragma unroll
        for (int ct = 0; ct < 16; ct++) {
            bf16x8 b = Bptr[(kt * 16 + ct) * 64];
            acc[ct] = __builtin_amdgcn_mfma_f32_16x16x32_bf16(a, b, acc[ct], 0, 0, 0);
        }
    }
    int rbase = r0 + (L >> 4) * 4;
    int cl = L & 15;
#pragma unroll
    for (int ct = 0; ct < 16; ct++) {
        int col = ct * 16 + cl;
#pragma unroll
        for (int r = 0; r < 4; r++) {
            int row = rbase + r;
            float v = acc[ct][r];
            if (col < 128)
                xr[(size_t)row * 128 + col] = f2bf(v);
            else
                accbf[(size_t)row * 128 + (col - 128)] = f2bf(v + bias[col - 128]);
        }
    }
}

// ================= gather-aggregate + relu + bf16 convert =================
// one wave per node; 4 edges per dwordx4 load; index loads are group-uniform dword
// loads (HW broadcast) instead of ds_bpermute — no LDS-pipe serialization.
__global__ __launch_bounds__(256) void agg_relu_cvt(const unsigned short* __restrict__ xr,
                                                    const unsigned short* __restrict__ accbf,
                                                    const int* __restrict__ off_,
                                                    const int* __restrict__ deg,
                                                    const int* __restrict__ csr_src,
                                                    unsigned short* __restrict__ out, int N) {
    int node = blockIdx.x * 4 + (threadIdx.x >> 6);
    if (node >= N) return;
    int L = threadIdx.x & 63;
    int g = L >> 4;
    int f = L & 15;
    int o = off_[node];
    int d = deg[node];
    uint4 arow = (uint4){0, 0, 0, 0};
    if (g == 0) arow = *(const uint4*)(accbf + (size_t)node * 128 + f * 8);

    const int* ip = csr_src + o + g;
    const unsigned short* xrf = xr + f * 8;

    float lo0 = 0.f, lo1 = 0.f, lo2 = 0.f, lo3 = 0.f;
    float hi0 = 0.f, hi1 = 0.f, hi2 = 0.f, hi3 = 0.f;

    int d4 = d & ~3;
#pragma unroll 4
    for (int k = 0; k < d4; k += 4) {
        int s = ip[k];  // group-uniform (16 lanes same addr -> broadcast)
        uint4 p = *(const uint4*)(xrf + (size_t)s * 128);
        lo0 += asf(p.x << 16); hi0 += asf(p.x & 0xFFFF0000u);
        lo1 += asf(p.y << 16); hi1 += asf(p.y & 0xFFFF0000u);
        lo2 += asf(p.z << 16); hi2 += asf(p.z & 0xFFFF0000u);
        lo3 += asf(p.w << 16); hi3 += asf(p.w & 0xFFFF0000u);
    }
    if (d4 + g < d) {
        int s = ip[d4];
        uint4 p = *(const uint4*)(xrf + (size_t)s * 128);
        lo0 += asf(p.x << 16); hi0 += asf(p.x & 0xFFFF0000u);
        lo1 += asf(p.y << 16); hi1 += asf(p.y & 0xFFFF0000u);
        lo2 += asf(p.z << 16); hi2 += asf(p.z & 0xFFFF0000u);
        lo3 += asf(p.w << 16); hi3 += asf(p.w & 0xFFFF0000u);
    }
    lo0 += __shfl_xor(lo0, 16, 64); hi0 += __shfl_xor(hi0, 16, 64);
    lo1 += __shfl_xor(lo1, 16, 64); hi1 += __shfl_xor(hi1, 16, 64);
    lo2 += __shfl_xor(lo2, 16, 64); hi2 += __shfl_xor(hi2, 16, 64);
    lo3 += __shfl_xor(lo3, 16, 64); hi3 += __shfl_xor(hi3, 16, 64);
    lo0 += __shfl_xor(lo0, 32, 64); hi0 += __shfl_xor(hi0, 32, 64);
    lo1 += __shfl_xor(lo1, 32, 64); hi1 += __shfl_xor(hi1, 32, 64);
    lo2 += __shfl_xor(lo2, 32, 64); hi2 += __shfl_xor(hi2, 32, 64);
    lo3 += __shfl_xor(lo3, 32, 64); hi3 += __shfl_xor(hi3, 32, 64);

    if (g == 0) {
        uint4 wv;
        wv.x = ((unsigned)f2bf(fmaxf(asf(arow.x & 0xFFFF0000u) + hi0, 0.f)) << 16)
             | f2bf(fmaxf(asf(arow.x << 16) + lo0, 0.f));
        wv.y = ((unsigned)f2bf(fmaxf(asf(arow.y & 0xFFFF0000u) + hi1, 0.f)) << 16)
             | f2bf(fmaxf(asf(arow.y << 16) + lo1, 0.f));
        wv.z = ((unsigned)f2bf(fmaxf(asf(arow.z & 0xFFFF0000u) + hi2, 0.f)) << 16)
             | f2bf(fmaxf(asf(arow.z << 16) + lo2, 0.f));
        wv.w = ((unsigned)f2bf(fmaxf(asf(arow.w & 0xFFFF0000u) + hi3, 0.f)) << 16)
             | f2bf(fmaxf(asf(arow.w << 16) + lo3, 0.f));
        *(uint4*)(out + (size_t)node * 128 + f * 8) = wv;
    }
}

// ================= final GEMM + fused log_softmax =================
__global__ __launch_bounds__(256) void gemm_final_ls(const unsigned short* __restrict__ x1bf,
                                                     const unsigned short* __restrict__ x2bf,
                                                     const unsigned short* __restrict__ Bsw,
                                                     const float* __restrict__ blin,
                                                     float* __restrict__ out, int N) {
    int wid = blockIdx.x * 4 + (threadIdx.x >> 6);
    int L = threadIdx.x & 63;
    int r0 = wid * 16;
    if (r0 >= N) return;
    int arow = r0 + (L & 15);
    f32x4 acc[3];
#pragma unroll
    for (int i = 0; i < 3; i++) acc[i] = (f32x4){0.f, 0.f, 0.f, 0.f};
#pragma unroll
    for (int kt = 0; kt < 8; kt++) {
        const unsigned short* Ab = (kt < 4) ? x1bf : x2bf;
        int kk = (kt & 3) * 32 + ((L >> 4) * 8);
        bf16x8 a = *((const bf16x8*)(Ab + (size_t)arow * 128 + kk));
#pragma unroll
        for (int ct = 0; ct < 3; ct++) {
            bf16x8 b = ((const bf16x8*)Bsw)[(kt * 3 + ct) * 64 + L];
            acc[ct] = __builtin_amdgcn_mfma_f32_16x16x32_bf16(a, b, acc[ct], 0, 0, 0);
        }
    }
    int rbase = r0 + (L >> 4) * 4;
    int cl = L & 15;
    float b0 = blin[cl], b1 = blin[16 + cl];
    float b2 = (cl < 8) ? blin[32 + cl] : 0.f;
#pragma unroll
    for (int r = 0; r < 4; r++) {
        int row = rbase + r;
        float v0 = acc[0][r] + b0;
        float v1 = acc[1][r] + b1;
        float v2 = (cl < 8) ? (acc[2][r] + b2) : -__builtin_inff();
        float m = fmaxf(fmaxf(v0, v1), v2);
#pragma unroll
        for (int off = 8; off >= 1; off >>= 1) m = fmaxf(m, __shfl_xor(m, off, 64));
        float e = __expf(v0 - m) + __expf(v1 - m) + ((cl < 8) ? __expf(v2 - m) : 0.f);
#pragma unroll
        for (int off = 8; off >= 1; off >>= 1) e += __shfl_xor(e, off, 64);
        float ls = m + __logf(e);
        float* op = out + (size_t)row * 40;
        op[cl] = v0 - ls;
        op[16 + cl] = v1 - ls;
        if (cl < 8) op[32 + cl] = v2 - ls;
    }
}

extern "C" void kernel_launch(void* const* d_in, const int* in_sizes, int n_in,
                              void* d_out, int out_size, void* d_ws, size_t ws_size,
                              hipStream_t stream) {
    const float* x      = (const float*)d_in[0];
    const int*   edge   = (const int*)d_in[1];
    const float* Wrel1  = (const float*)d_in[2];
    const float* brel1  = (const float*)d_in[3];
    const float* Wroot1 = (const float*)d_in[4];
    const float* Wrel2  = (const float*)d_in[5];
    const float* brel2  = (const float*)d_in[6];
    const float* Wroot2 = (const float*)d_in[7];
    const float* Wlin   = (const float*)d_in[8];
    const float* blin   = (const float*)d_in[9];

    const int N = in_sizes[0] / 128;
    const int E = in_sizes[1] / 2;
    const int* src = edge;
    const int* dst = edge + E;

    const int nblk  = (E + EPB - 1) / EPB;                    // 391
    const int nbuck = (N + BUCKET_SIZE - 1) / BUCKET_SIZE;    // 391

    char* ws = (char*)d_ws;
    size_t off = 0;
    auto alloc = [&](size_t bytes) -> void* {
        void* p = ws + off;
        off += (bytes + 255) & ~(size_t)255;
        return p;
    };
    unsigned short* x1bf = (unsigned short*)alloc((size_t)N * 128 * 2);
    unsigned short* x2bf = (unsigned short*)alloc((size_t)N * 128 * 2);
    unsigned short* xr   = (unsigned short*)alloc((size_t)N * 128 * 2);
    unsigned short* accbf= (unsigned short*)alloc((size_t)N * 128 * 2);
    unsigned short* bsw1 = (unsigned short*)alloc(32768 * 2);
    unsigned short* bsw2 = (unsigned short*)alloc(32768 * 2);
    unsigned short* bswL = (unsigned short*)alloc(12288 * 2);
    int* hist       = (int*)alloc((size_t)nbuck * nblk * 4);
    int* bucketTot  = (int*)alloc((size_t)nbuck * 4);
    int* bucketBase = (int*)alloc((size_t)(nbuck + 1) * 4);
    int* part       = (int*)alloc((size_t)E * 4);
    int* csr_src    = (int*)alloc((size_t)E * 4);
    int* off_       = (int*)alloc((size_t)N * 4);
    int* deg_       = (int*)alloc((size_t)N * 4);

    const int rowTiles = (N + 15) / 16;
    const int gemmBlocks = (rowTiles + 3) / 4;
    const int nodeBlocks = (N + 3) / 4;

    // K1: weight swizzles + edge histogram
    prep<<<304 + nblk, 256, 0, stream>>>(Wrel1, Wroot1, Wrel2, Wroot2, Wlin, dst,
                                         bsw1, bsw2, bswL, hist, E, nblk, nbuck);
    // K2: scans
    bucket_total<<<nbuck, 256, 0, stream>>>(hist, bucketTot, nblk);
    bucket_scan<<<1, 256, 0, stream>>>(bucketTot, bucketBase, nbuck);
    block_scan<<<nbuck, 256, 0, stream>>>(hist, bucketBase, nblk);
    // K3: partition
    edge_part<<<nblk, 256, 0, stream>>>(src, dst, hist, part, E, nblk, nbuck);
    // K4: CSR finalize (391 blocks) + layer-1 GEMM (independent) in one launch
    csrfin_gemm1<<<nbuck + gemmBlocks, 256, 0, stream>>>(part, bucketBase, off_, deg_, csr_src,
                                                         x, bsw1, brel1, xr, accbf, N, nbuck);
    // K5: layer-1 aggregation
    agg_relu_cvt<<<nodeBlocks, 256, 0, stream>>>(xr, accbf, off_, deg_, csr_src, x1bf, N);
    // K6: layer-2 GEMM
    gemm_layer2<<<gemmBlocks, 256, 0, stream>>>(x1bf, bsw2, brel2, xr, accbf, N);
    // K7: layer-2 aggregation
    agg_relu_cvt<<<nodeBlocks, 256, 0, stream>>>(xr, accbf, off_, deg_, csr_src, x2bf, N);
    // K8: classifier + fused log_softmax
    gemm_final_ls<<<gemmBlocks, 256, 0, stream>>>(x1bf, x2bf, bswL, blin, (float*)d_out, N);
}

// Round 9
// 336.388 us; speedup vs baseline: 8.9722x; 1.0290x over previous
//
#include <hip/hip_runtime.h>
#include <hip/hip_bf16.h>

typedef __attribute__((ext_vector_type(8))) short bf16x8;
typedef __attribute__((ext_vector_type(4))) float f32x4;
typedef __attribute__((ext_vector_type(2))) float f32x2;

#define EPB 4096         // edges per partition block
#define BUCKET_BITS 8
#define BUCKET_SIZE 256  // nodes per bucket
#define MAXBUCK 512

static __device__ __forceinline__ unsigned short f2bf(float f) {
    union { float f; unsigned u; } v; v.f = f;
    unsigned r = v.u + 0x7FFF + ((v.u >> 16) & 1);
    return (unsigned short)(r >> 16);
}
static __device__ __forceinline__ float asf(unsigned u) {
    union { unsigned u; float f; } v; v.u = u;
    return v.f;
}
// packed bf16 pair -> f32x2 {lo, hi}
static __device__ __forceinline__ f32x2 cvt2(unsigned u) {
    f32x2 r;
    r.x = asf(u << 16);
    r.y = asf(u & 0xFFFF0000u);
    return r;
}

// ================= K1: prep — weight swizzles + edge histogram (merged) =================
__global__ __launch_bounds__(256) void prep(const float* __restrict__ Wrel1,
                                            const float* __restrict__ Wroot1,
                                            const float* __restrict__ Wrel2,
                                            const float* __restrict__ Wroot2,
                                            const float* __restrict__ Wlin,
                                            const int* __restrict__ dst,
                                            unsigned short* __restrict__ bsw1,
                                            unsigned short* __restrict__ bsw2,
                                            unsigned short* __restrict__ bswL,
                                            int* __restrict__ hist,
                                            int E, int nblk, int nbuck) {
    __shared__ int h[MAXBUCK];
    int blk = blockIdx.x, t = threadIdx.x;
    if (blk < 256) {
        const float* Wrel  = (blk < 128) ? Wrel1 : Wrel2;
        const float* Wroot = (blk < 128) ? Wroot1 : Wroot2;
        unsigned short* bsw = (blk < 128) ? bsw1 : bsw2;
        int idx = (blk & 127) * 256 + t;  // 32768 total
        int j = idx & 7, L = (idx >> 3) & 63, ct = (idx >> 9) & 15, kt = idx >> 13;
        int k = kt * 32 + ((L >> 4) * 8) + j;
        int c = ct * 16 + (L & 15);
        float v = (c < 128) ? Wrel[k * 128 + c] : Wroot[k * 128 + (c - 128)];
        bsw[idx] = f2bf(v);
    } else if (blk < 304) {
        int idx = (blk - 256) * 256 + t;  // 12288 total
        int tt = idx;
        int j = tt & 7; tt >>= 3;
        int L = tt & 63; tt >>= 6;
        int ct = tt % 3;
        int kt = tt / 3;
        int k = kt * 32 + ((L >> 4) * 8) + j;
        int c = ct * 16 + (L & 15);
        float v = (c < 40) ? Wlin[k * 40 + c] : 0.f;
        bswL[idx] = f2bf(v);
    } else {
        int hb = blk - 304;
        for (int i = t; i < MAXBUCK; i += 256) h[i] = 0;
        __syncthreads();
        int e0 = hb * EPB;
#pragma unroll
        for (int it = 0; it < EPB / 256; it++) {
            int e = e0 + it * 256 + t;
            if (e < E) atomicAdd(&h[dst[e] >> BUCKET_BITS], 1);
        }
        __syncthreads();
        for (int i = t; i < nbuck; i += 256) hist[i * nblk + hb] = h[i];
    }
}

// ================= K2a: bucket totals =================
__global__ __launch_bounds__(256) void bucket_total(const int* __restrict__ hist,
                                                    int* __restrict__ total, int nblk) {
    __shared__ int s[256];
    int b = blockIdx.x, t = threadIdx.x;
    int v = 0;
    for (int i = t; i < nblk; i += 256) v += hist[b * nblk + i];
    s[t] = v; __syncthreads();
#pragma unroll
    for (int o = 128; o >= 1; o >>= 1) {
        if (t < o) s[t] += s[t + o];
        __syncthreads();
    }
    if (t == 0) total[b] = s[0];
}

// ================= K2b: exclusive scan of bucket totals (pair-scan, nbuck <= 512) =================
__global__ __launch_bounds__(256) void bucket_scan(const int* __restrict__ total,
                                                   int* __restrict__ base, int nbuck) {
    __shared__ int s[256];
    int t = threadIdx.x;
    int e0 = (2 * t < nbuck) ? total[2 * t] : 0;
    int e1 = (2 * t + 1 < nbuck) ? total[2 * t + 1] : 0;
    int ps = e0 + e1;
    s[t] = ps; __syncthreads();
#pragma unroll
    for (int o = 1; o < 256; o <<= 1) {
        int x = (t >= o) ? s[t - o] : 0;
        __syncthreads();
        s[t] += x; __syncthreads();
    }
    int pbase = s[t] - ps;
    if (2 * t <= nbuck) base[2 * t] = pbase;
    if (2 * t + 1 <= nbuck) base[2 * t + 1] = pbase + e0;
}

// ================= K2c: per-bucket scan over blocks -> global slot bases (in place) =================
__global__ __launch_bounds__(256) void block_scan(int* __restrict__ hist,
                                                  const int* __restrict__ base, int nblk) {
    __shared__ int s[256];
    int b = blockIdx.x, t = threadIdx.x;
    int carryv = base[b];
    for (int start = 0; start < nblk; start += 256) {
        int i = start + t;
        int v = (i < nblk) ? hist[b * nblk + i] : 0;
        s[t] = v; __syncthreads();
#pragma unroll
        for (int o = 1; o < 256; o <<= 1) {
            int x = (t >= o) ? s[t - o] : 0;
            __syncthreads();
            s[t] += x; __syncthreads();
        }
        int excl = s[t] - v + carryv;
        if (i < nblk) hist[b * nblk + i] = excl;
        carryv += s[255];
        __syncthreads();
    }
}

// ================= K3: per-chunk LDS counting sort -> bucket-sorted packed records =================
__global__ __launch_bounds__(256) void edge_part(const int* __restrict__ src,
                                                 const int* __restrict__ dst,
                                                 const int* __restrict__ hist,  // block bases
                                                 int* __restrict__ part,
                                                 int E, int nblk, int nbuck) {
    __shared__ int hcnt[MAXBUCK];
    __shared__ int lstart[MAXBUCK];
    __shared__ int cur[MAXBUCK];
    __shared__ int gbase[MAXBUCK];
    __shared__ int s2[256];
    __shared__ int sdst[EPB];  // 16 KB
    __shared__ int ssrc[EPB];  // 16 KB
    int t = threadIdx.x, blk = blockIdx.x;
    int e0 = blk * EPB;
    int cnt = E - e0; if (cnt > EPB) cnt = EPB;
    for (int i = t; i < MAXBUCK; i += 256) hcnt[i] = 0;
    for (int i = t; i < nbuck; i += 256) gbase[i] = hist[i * nblk + blk];
    __syncthreads();
    int myd[EPB / 256], mys[EPB / 256];
#pragma unroll
    for (int it = 0; it < EPB / 256; it++) {
        int i = it * 256 + t;
        if (i < cnt) {
            myd[it] = dst[e0 + i];
            mys[it] = src[e0 + i];
            atomicAdd(&hcnt[myd[it] >> BUCKET_BITS], 1);
        }
    }
    __syncthreads();
    int p0 = hcnt[2 * t], p1 = hcnt[2 * t + 1];
    int ps = p0 + p1;
    s2[t] = ps; __syncthreads();
#pragma unroll
    for (int o = 1; o < 256; o <<= 1) {
        int x = (t >= o) ? s2[t - o] : 0;
        __syncthreads();
        s2[t] += x; __syncthreads();
    }
    int pbase = s2[t] - ps;
    lstart[2 * t] = pbase; lstart[2 * t + 1] = pbase + p0;
    cur[2 * t] = 0; cur[2 * t + 1] = 0;
    __syncthreads();
#pragma unroll
    for (int it = 0; it < EPB / 256; it++) {
        int i = it * 256 + t;
        if (i < cnt) {
            int b = myd[it] >> BUCKET_BITS;
            int p = lstart[b] + atomicAdd(&cur[b], 1);
            sdst[p] = myd[it];
            ssrc[p] = mys[it];
        }
    }
    __syncthreads();
    for (int i = t; i < cnt; i += 256) {
        int d = sdst[i], s = ssrc[i];
        int b = d >> BUCKET_BITS;
        part[gbase[b] + (i - lstart[b])] = ((d & (BUCKET_SIZE - 1)) << 17) | s;
    }
}

// ================= K4: csr_finalize (blocks 0..nbuck-1) + layer-1 GEMM (rest), merged =================
__global__ __launch_bounds__(256) void csrfin_gemm1(const int* __restrict__ part,
                                                    const int* __restrict__ bucketBase,
                                                    int* __restrict__ off_,
                                                    int* __restrict__ deg_,
                                                    int* __restrict__ csr_src,
                                                    const float* __restrict__ x,
                                                    const unsigned short* __restrict__ Bsw,
                                                    const float* __restrict__ bias,
                                                    unsigned short* __restrict__ xr,
                                                    unsigned short* __restrict__ accbf,
                                                    int N, int nbuck) {
    __shared__ int cur[BUCKET_SIZE];
    __shared__ int h[BUCKET_SIZE];
    __shared__ int tsum[256];
    int t = threadIdx.x;
    if (blockIdx.x < (unsigned)nbuck) {
        int b = blockIdx.x;
        int lo = bucketBase[b], hi = bucketBase[b + 1];
        int n0 = b * BUCKET_SIZE;
        h[t] = 0;
        __syncthreads();
        for (int i = lo + t; i < hi; i += 256) atomicAdd(&h[part[i] >> 17], 1);
        __syncthreads();
        int hv = h[t];
        tsum[t] = hv;
        __syncthreads();
#pragma unroll
        for (int o = 1; o < 256; o <<= 1) {
            int xx = (t >= o) ? tsum[t - o] : 0;
            __syncthreads();
            tsum[t] += xx;
            __syncthreads();
        }
        int st = tsum[t] - hv;
        cur[t] = st;
        int node = n0 + t;
        if (node < N) { off_[node] = lo + st; deg_[node] = hv; }
        __syncthreads();
        for (int i = lo + t; i < hi; i += 256) {
            int rec = part[i];
            int p = atomicAdd(&cur[rec >> 17], 1);
            csr_src[lo + p] = rec & 0x1FFFF;
        }
    } else {
        int wid = (blockIdx.x - nbuck) * 4 + (t >> 6);
        int L = t & 63;
        int r0 = wid * 16;
        if (r0 >= N) return;
        int arow = r0 + (L & 15);
        const bf16x8* Bptr = ((const bf16x8*)Bsw) + L;
        f32x4 acc[16];
#pragma unroll
        for (int i = 0; i < 16; i++) acc[i] = (f32x4){0.f, 0.f, 0.f, 0.f};
#pragma unroll
        for (int kt = 0; kt < 4; kt++) {
            const float* Arow = x + (size_t)arow * 128 + ((L >> 4) * 8) + kt * 32;
            float4 a0 = *(const float4*)Arow;
            float4 a1 = *(const float4*)(Arow + 4);
            bf16x8 a;
            a[0] = (short)f2bf(a0.x); a[1] = (short)f2bf(a0.y);
            a[2] = (short)f2bf(a0.z); a[3] = (short)f2bf(a0.w);
            a[4] = (short)f2bf(a1.x); a[5] = (short)f2bf(a1.y);
            a[6] = (short)f2bf(a1.z); a[7] = (short)f2bf(a1.w);
#pragma unroll
            for (int ct = 0; ct < 16; ct++) {
                bf16x8 b = Bptr[(kt * 16 + ct) * 64];
                acc[ct] = __builtin_amdgcn_mfma_f32_16x16x32_bf16(a, b, acc[ct], 0, 0, 0);
            }
        }
        int rbase = r0 + (L >> 4) * 4;
        int cl = L & 15;
#pragma unroll
        for (int ct = 0; ct < 16; ct++) {
            int col = ct * 16 + cl;
#pragma unroll
            for (int r = 0; r < 4; r++) {
                int row = rbase + r;
                float v = acc[ct][r];
                if (col < 128)
                    xr[(size_t)row * 128 + col] = f2bf(v);
                else
                    accbf[(size_t)row * 128 + (col - 128)] = f2bf(v + bias[col - 128]);
            }
        }
    }
}

// ================= layer-2 GEMM (bf16 A, B staged in LDS, grid-stride tiles) =================
__global__ __launch_bounds__(256) void gemm_layer2(const unsigned short* __restrict__ Abf,
                                                   const unsigned short* __restrict__ Bsw,
                                                   const float* __restrict__ bias,
                                                   unsigned short* __restrict__ xr,
                                                   unsigned short* __restrict__ accbf, int N) {
    __shared__ unsigned short Bs[32768];  // 64 KB
    int t = threadIdx.x;
    {
        uint4* d4 = (uint4*)Bs;
        const uint4* s4 = (const uint4*)Bsw;
#pragma unroll
        for (int i = 0; i < 16; i++) d4[t + i * 256] = s4[t + i * 256];
    }
    __syncthreads();
    int w = t >> 6, L = t & 63;
    int nTiles = (N + 15) / 16;
    for (int tile = blockIdx.x * 4 + w; tile < nTiles; tile += gridDim.x * 4) {
        int r0 = tile * 16;
        int arow = r0 + (L & 15);
        f32x4 acc[16];
#pragma unroll
        for (int i = 0; i < 16; i++) acc[i] = (f32x4){0.f, 0.f, 0.f, 0.f};
#pragma unroll
        for (int kt = 0; kt < 4; kt++) {
            bf16x8 a = *((const bf16x8*)(Abf + (size_t)arow * 128 + ((L >> 4) * 8) + kt * 32));
#pragma unroll
            for (int ct = 0; ct < 16; ct++) {
                bf16x8 b = *(const bf16x8*)(Bs + (((kt * 16 + ct) * 64) + L) * 8);
                acc[ct] = __builtin_amdgcn_mfma_f32_16x16x32_bf16(a, b, acc[ct], 0, 0, 0);
            }
        }
        int rbase = r0 + (L >> 4) * 4;
        int cl = L & 15;
#pragma unroll
        for (int ct = 0; ct < 16; ct++) {
            int col = ct * 16 + cl;
#pragma unroll
            for (int r = 0; r < 4; r++) {
                int row = rbase + r;
                float v = acc[ct][r];
                if (col < 128)
                    xr[(size_t)row * 128 + col] = f2bf(v);
                else
                    accbf[(size_t)row * 128 + (col - 128)] = f2bf(v + bias[col - 128]);
            }
        }
    }
}

// ================= gather-aggregate + relu + bf16 convert =================
// one wave per node; 4 edges per dwordx4 load; f32x2 accumulators -> v_pk_add_f32
__global__ __launch_bounds__(256) void agg_relu_cvt(const unsigned short* __restrict__ xr,
                                                    const unsigned short* __restrict__ accbf,
                                                    const int* __restrict__ off_,
                                                    const int* __restrict__ deg,
                                                    const int* __restrict__ csr_src,
                                                    unsigned short* __restrict__ out, int N) {
    int node = blockIdx.x * 4 + (threadIdx.x >> 6);
    if (node >= N) return;
    int L = threadIdx.x & 63;
    int g = L >> 4;
    int f = L & 15;
    int o = off_[node];
    int d = deg[node];
    uint4 arow = (uint4){0, 0, 0, 0};
    if (g == 0) arow = *(const uint4*)(accbf + (size_t)node * 128 + f * 8);

    const int* ip = csr_src + o + g;
    const unsigned short* xrf = xr + f * 8;

    f32x2 a0 = (f32x2){0.f, 0.f}, a1 = (f32x2){0.f, 0.f};
    f32x2 a2 = (f32x2){0.f, 0.f}, a3 = (f32x2){0.f, 0.f};

    int d4 = d & ~3;
#pragma unroll 4
    for (int k = 0; k < d4; k += 4) {
        int s = ip[k];  // group-uniform (16 lanes same addr -> broadcast)
        uint4 p = *(const uint4*)(xrf + (size_t)s * 128);
        a0 += cvt2(p.x);
        a1 += cvt2(p.y);
        a2 += cvt2(p.z);
        a3 += cvt2(p.w);
    }
    if (d4 + g < d) {
        int s = ip[d4];
        uint4 p = *(const uint4*)(xrf + (size_t)s * 128);
        a0 += cvt2(p.x);
        a1 += cvt2(p.y);
        a2 += cvt2(p.z);
        a3 += cvt2(p.w);
    }
    a0.x += __shfl_xor(a0.x, 16, 64); a0.y += __shfl_xor(a0.y, 16, 64);
    a1.x += __shfl_xor(a1.x, 16, 64); a1.y += __shfl_xor(a1.y, 16, 64);
    a2.x += __shfl_xor(a2.x, 16, 64); a2.y += __shfl_xor(a2.y, 16, 64);
    a3.x += __shfl_xor(a3.x, 16, 64); a3.y += __shfl_xor(a3.y, 16, 64);
    a0.x += __shfl_xor(a0.x, 32, 64); a0.y += __shfl_xor(a0.y, 32, 64);
    a1.x += __shfl_xor(a1.x, 32, 64); a1.y += __shfl_xor(a1.y, 32, 64);
    a2.x += __shfl_xor(a2.x, 32, 64); a2.y += __shfl_xor(a2.y, 32, 64);
    a3.x += __shfl_xor(a3.x, 32, 64); a3.y += __shfl_xor(a3.y, 32, 64);

    if (g == 0) {
        uint4 wv;
        wv.x = ((unsigned)f2bf(fmaxf(asf(arow.x & 0xFFFF0000u) + a0.y, 0.f)) << 16)
             | f2bf(fmaxf(asf(arow.x << 16) + a0.x, 0.f));
        wv.y = ((unsigned)f2bf(fmaxf(asf(arow.y & 0xFFFF0000u) + a1.y, 0.f)) << 16)
             | f2bf(fmaxf(asf(arow.y << 16) + a1.x, 0.f));
        wv.z = ((unsigned)f2bf(fmaxf(asf(arow.z & 0xFFFF0000u) + a2.y, 0.f)) << 16)
             | f2bf(fmaxf(asf(arow.z << 16) + a2.x, 0.f));
        wv.w = ((unsigned)f2bf(fmaxf(asf(arow.w & 0xFFFF0000u) + a3.y, 0.f)) << 16)
             | f2bf(fmaxf(asf(arow.w << 16) + a3.x, 0.f));
        *(uint4*)(out + (size_t)node * 128 + f * 8) = wv;
    }
}

// ================= final GEMM + fused log_softmax (B in LDS, grid-stride) =================
__global__ __launch_bounds__(256) void gemm_final_ls(const unsigned short* __restrict__ x1bf,
                                                     const unsigned short* __restrict__ x2bf,
                                                     const unsigned short* __restrict__ Bsw,
                                                     const float* __restrict__ blin,
                                                     float* __restrict__ out, int N) {
    __shared__ unsigned short Bs[12288];  // 24 KB
    int t = threadIdx.x;
    {
        uint4* d4 = (uint4*)Bs;
        const uint4* s4 = (const uint4*)Bsw;
#pragma unroll
        for (int i = 0; i < 6; i++) d4[t + i * 256] = s4[t + i * 256];
    }
    __syncthreads();
    int w = t >> 6, L = t & 63;
    int cl = L & 15;
    float b0 = blin[cl], b1 = blin[16 + cl];
    float b2 = (cl < 8) ? blin[32 + cl] : 0.f;
    int nTiles = (N + 15) / 16;
    for (int tile = blockIdx.x * 4 + w; tile < nTiles; tile += gridDim.x * 4) {
        int r0 = tile * 16;
        int arow = r0 + (L & 15);
        f32x4 acc[3];
#pragma unroll
        for (int i = 0; i < 3; i++) acc[i] = (f32x4){0.f, 0.f, 0.f, 0.f};
#pragma unroll
        for (int kt = 0; kt < 8; kt++) {
            const unsigned short* Ab = (kt < 4) ? x1bf : x2bf;
            int kk = (kt & 3) * 32 + ((L >> 4) * 8);
            bf16x8 a = *((const bf16x8*)(Ab + (size_t)arow * 128 + kk));
#pragma unroll
            for (int ct = 0; ct < 3; ct++) {
                bf16x8 b = *(const bf16x8*)(Bs + (((kt * 3 + ct) * 64) + L) * 8);
                acc[ct] = __builtin_amdgcn_mfma_f32_16x16x32_bf16(a, b, acc[ct], 0, 0, 0);
            }
        }
        int rbase = r0 + (L >> 4) * 4;
#pragma unroll
        for (int r = 0; r < 4; r++) {
            int row = rbase + r;
            float v0 = acc[0][r] + b0;
            float v1 = acc[1][r] + b1;
            float v2 = (cl < 8) ? (acc[2][r] + b2) : -__builtin_inff();
            float m = fmaxf(fmaxf(v0, v1), v2);
#pragma unroll
            for (int off = 8; off >= 1; off >>= 1) m = fmaxf(m, __shfl_xor(m, off, 64));
            float e = __expf(v0 - m) + __expf(v1 - m) + ((cl < 8) ? __expf(v2 - m) : 0.f);
#pragma unroll
            for (int off = 8; off >= 1; off >>= 1) e += __shfl_xor(e, off, 64);
            float ls = m + __logf(e);
            float* op = out + (size_t)row * 40;
            op[cl] = v0 - ls;
            op[16 + cl] = v1 - ls;
            if (cl < 8) op[32 + cl] = v2 - ls;
        }
    }
}

extern "C" void kernel_launch(void* const* d_in, const int* in_sizes, int n_in,
                              void* d_out, int out_size, void* d_ws, size_t ws_size,
                              hipStream_t stream) {
    const float* x      = (const float*)d_in[0];
    const int*   edge   = (const int*)d_in[1];
    const float* Wrel1  = (const float*)d_in[2];
    const float* brel1  = (const float*)d_in[3];
    const float* Wroot1 = (const float*)d_in[4];
    const float* Wrel2  = (const float*)d_in[5];
    const float* brel2  = (const float*)d_in[6];
    const float* Wroot2 = (const float*)d_in[7];
    const float* Wlin   = (const float*)d_in[8];
    const float* blin   = (const float*)d_in[9];

    const int N = in_sizes[0] / 128;
    const int E = in_sizes[1] / 2;
    const int* src = edge;
    const int* dst = edge + E;

    const int nblk  = (E + EPB - 1) / EPB;                    // 391
    const int nbuck = (N + BUCKET_SIZE - 1) / BUCKET_SIZE;    // 391

    char* ws = (char*)d_ws;
    size_t off = 0;
    auto alloc = [&](size_t bytes) -> void* {
        void* p = ws + off;
        off += (bytes + 255) & ~(size_t)255;
        return p;
    };
    unsigned short* x1bf = (unsigned short*)alloc((size_t)N * 128 * 2);
    unsigned short* x2bf = (unsigned short*)alloc((size_t)N * 128 * 2);
    unsigned short* xr   = (unsigned short*)alloc((size_t)N * 128 * 2);
    unsigned short* accbf= (unsigned short*)alloc((size_t)N * 128 * 2);
    unsigned short* bsw1 = (unsigned short*)alloc(32768 * 2);
    unsigned short* bsw2 = (unsigned short*)alloc(32768 * 2);
    unsigned short* bswL = (unsigned short*)alloc(12288 * 2);
    int* hist       = (int*)alloc((size_t)nbuck * nblk * 4);
    int* bucketTot  = (int*)alloc((size_t)nbuck * 4);
    int* bucketBase = (int*)alloc((size_t)(nbuck + 1) * 4);
    int* part       = (int*)alloc((size_t)E * 4);
    int* csr_src    = (int*)alloc((size_t)E * 4);
    int* off_       = (int*)alloc((size_t)N * 4);
    int* deg_       = (int*)alloc((size_t)N * 4);

    const int rowTiles = (N + 15) / 16;
    const int gemmBlocks = (rowTiles + 3) / 4;
    const int nodeBlocks = (N + 3) / 4;

    // K1: weight swizzles + edge histogram
    prep<<<304 + nblk, 256, 0, stream>>>(Wrel1, Wroot1, Wrel2, Wroot2, Wlin, dst,
                                         bsw1, bsw2, bswL, hist, E, nblk, nbuck);
    // K2: scans
    bucket_total<<<nbuck, 256, 0, stream>>>(hist, bucketTot, nblk);
    bucket_scan<<<1, 256, 0, stream>>>(bucketTot, bucketBase, nbuck);
    block_scan<<<nbuck, 256, 0, stream>>>(hist, bucketBase, nblk);
    // K3: partition
    edge_part<<<nblk, 256, 0, stream>>>(src, dst, hist, part, E, nblk, nbuck);
    // K4: CSR finalize (391 blocks) + layer-1 GEMM (independent) in one launch
    csrfin_gemm1<<<nbuck + gemmBlocks, 256, 0, stream>>>(part, bucketBase, off_, deg_, csr_src,
                                                         x, bsw1, brel1, xr, accbf, N, nbuck);
    // K5: layer-1 aggregation
    agg_relu_cvt<<<nodeBlocks, 256, 0, stream>>>(xr, accbf, off_, deg_, csr_src, x1bf, N);
    // K6: layer-2 GEMM (B in LDS, grid-stride)
    gemm_layer2<<<512, 256, 0, stream>>>(x1bf, bsw2, brel2, xr, accbf, N);
    // K7: layer-2 aggregation
    agg_relu_cvt<<<nodeBlocks, 256, 0, stream>>>(xr, accbf, off_, deg_, csr_src, x2bf, N);
    // K8: classifier + fused log_softmax (B in LDS, grid-stride)
    gemm_final_ls<<<512, 256, 0, stream>>>(x1bf, x2bf, bswL, blin, (float*)d_out, N);
}